// Round 1
// baseline (752.389 us; speedup 1.0000x reference)
//
#include <hip/hip_runtime.h>

typedef __bf16 bf16x8 __attribute__((ext_vector_type(8)));
typedef float floatx4 __attribute__((ext_vector_type(4)));
typedef unsigned short ushort8 __attribute__((ext_vector_type(8)));

#define L_SEQ 2048
#define D_MODEL 1024
#define D_INNER 2048
#define D_STATE 16
#define DT_RANK 64

__device__ __forceinline__ unsigned short f32_bf16(float f) {
  unsigned int u = __builtin_bit_cast(unsigned int, f);
  u += 0x7fffu + ((u >> 16) & 1u);
  return (unsigned short)(u >> 16);
}

// ---------------- converts ----------------
__global__ __launch_bounds__(256) void cvt_f32_bf16_4(const float* __restrict__ in,
                                                      unsigned short* __restrict__ out, int n4) {
  int i = blockIdx.x * 256 + threadIdx.x;
  if (i < n4) {
    float4 v = ((const float4*)in)[i];
    ushort4 o;
    o.x = f32_bf16(v.x); o.y = f32_bf16(v.y); o.z = f32_bf16(v.z); o.w = f32_bf16(v.w);
    ((ushort4*)out)[i] = o;
  }
}

// W_xproj (96 x 2048) -> bf16 padded to (128 x 2048)
__global__ __launch_bounds__(256) void cvt_pad_xproj(const float* __restrict__ in,
                                                     unsigned short* __restrict__ out) {
  int i = blockIdx.x * 256 + threadIdx.x;  // < 128*2048
  int r = i >> 11, c = i & 2047;
  out[i] = (r < 96) ? f32_bf16(in[r * 2048 + c]) : (unsigned short)0;
}

// proj[:, :64] f32 (stride 128) -> dtlow bf16 [2048][64]
__global__ __launch_bounds__(256) void cvt_dtlow(const float* __restrict__ proj,
                                                 unsigned short* __restrict__ out) {
  int i = blockIdx.x * 256 + threadIdx.x;  // < 2048*64
  out[i] = f32_bf16(proj[(i >> 6) * 128 + (i & 63)]);
}

// ---------------- layernorm -> bf16 ----------------
__global__ __launch_bounds__(256) void ln_kernel(const float* __restrict__ x,
                                                 const float* __restrict__ w,
                                                 const float* __restrict__ b,
                                                 unsigned short* __restrict__ xn) {
  int row = blockIdx.x, tid = threadIdx.x;
  const float4 v = ((const float4*)(x + (size_t)row * D_MODEL))[tid];
  float s = v.x + v.y + v.z + v.w;
  float q = v.x * v.x + v.y * v.y + v.z * v.z + v.w * v.w;
#pragma unroll
  for (int o = 1; o < 64; o <<= 1) {
    s += __shfl_xor(s, o);
    q += __shfl_xor(q, o);
  }
  __shared__ float red[8];
  int wv = tid >> 6;
  if ((tid & 63) == 0) { red[wv] = s; red[4 + wv] = q; }
  __syncthreads();
  s = red[0] + red[1] + red[2] + red[3];
  q = red[4] + red[5] + red[6] + red[7];
  float mu = s * (1.f / 1024.f);
  float var = q * (1.f / 1024.f) - mu * mu;
  float rs = rsqrtf(var + 1e-5f);
  float4 wv4 = ((const float4*)w)[tid];
  float4 bv4 = ((const float4*)b)[tid];
  ushort4 o;
  o.x = f32_bf16((v.x - mu) * rs * wv4.x + bv4.x);
  o.y = f32_bf16((v.y - mu) * rs * wv4.y + bv4.y);
  o.z = f32_bf16((v.z - mu) * rs * wv4.z + bv4.z);
  o.w = f32_bf16((v.w - mu) * rs * wv4.w + bv4.w);
  ((ushort4*)(xn + (size_t)row * D_MODEL))[tid] = o;
}

// ---------------- GEMM: C[M][N] = A[M][K] * B[N][K]^T (bf16 in, f32 out) ----------------
// EPI: 0 = plain, 1 = softplus(v + bias[col]), 2 = v + extra[row*N+col]
#define BM 128
#define BN 128
#define BKK 32
#define LDW 40  // 32 + 8 pad (keeps 16B alignment, breaks bank conflicts)

template <int EPI>
__global__ __launch_bounds__(256) void gemm_bt(const unsigned short* __restrict__ A,
                                               const unsigned short* __restrict__ B,
                                               float* __restrict__ C, int M, int N, int K,
                                               const float* __restrict__ extra) {
  __shared__ unsigned short As[BM * LDW];
  __shared__ unsigned short Bs[BN * LDW];
  const int tid = threadIdx.x;
  const int lane = tid & 63, wave = tid >> 6;
  const int wr = wave >> 1, wc = wave & 1;
  const int rl = lane & 15, kg = lane >> 4;
  const int bx = blockIdx.x, by = blockIdx.y;
  const unsigned short* Ab = A + (size_t)by * BM * K;
  const unsigned short* Bb = B + (size_t)bx * BN * K;
  floatx4 acc[4][4] = {};
  for (int k0 = 0; k0 < K; k0 += BKK) {
#pragma unroll
    for (int c = tid; c < 512; c += 256) {
      int row = c >> 2, kp = (c & 3) << 3;
      *(ushort8*)&As[row * LDW + kp] = *(const ushort8*)(Ab + (size_t)row * K + k0 + kp);
    }
#pragma unroll
    for (int c = tid; c < 512; c += 256) {
      int row = c >> 2, kp = (c & 3) << 3;
      *(ushort8*)&Bs[row * LDW + kp] = *(const ushort8*)(Bb + (size_t)row * K + k0 + kp);
    }
    __syncthreads();
    bf16x8 af[4], bfr[4];
#pragma unroll
    for (int m = 0; m < 4; ++m)
      af[m] = *(const bf16x8*)&As[(wr * 64 + m * 16 + rl) * LDW + kg * 8];
#pragma unroll
    for (int n = 0; n < 4; ++n)
      bfr[n] = *(const bf16x8*)&Bs[(wc * 64 + n * 16 + rl) * LDW + kg * 8];
#pragma unroll
    for (int m = 0; m < 4; ++m)
#pragma unroll
      for (int n = 0; n < 4; ++n)
        acc[m][n] = __builtin_amdgcn_mfma_f32_16x16x32_bf16(af[m], bfr[n], acc[m][n], 0, 0, 0);
    __syncthreads();
  }
#pragma unroll
  for (int m = 0; m < 4; ++m) {
#pragma unroll
    for (int n = 0; n < 4; ++n) {
      int col = bx * BN + wc * 64 + n * 16 + rl;
#pragma unroll
      for (int j = 0; j < 4; ++j) {
        int rowg = by * BM + wr * 64 + m * 16 + kg * 4 + j;
        float v = acc[m][n][j];
        if (EPI == 1) {
          v += extra[col];
          v = (v > 20.f) ? v : log1pf(__expf(v));
        }
        if (EPI == 2) v += extra[(size_t)rowg * N + col];
        C[(size_t)rowg * N + col] = v;
      }
    }
  }
}

// ---------------- causal depthwise conv (k=4) + SiLU ----------------
__global__ __launch_bounds__(256) void conv_silu_kernel(const float* __restrict__ xz,
                                                        const float* __restrict__ cw,
                                                        const float* __restrict__ cb,
                                                        float* __restrict__ xconv,
                                                        unsigned short* __restrict__ xconv_bf) {
  int d = blockIdx.x * 256 + threadIdx.x;  // 0..2047
  int lb = blockIdx.y * 8;
  float w0 = cw[d * 4 + 0], w1 = cw[d * 4 + 1], w2 = cw[d * 4 + 2], w3 = cw[d * 4 + 3];
  float bias = cb[d];
  float xm3 = (lb >= 3) ? xz[(size_t)(lb - 3) * 4096 + d] : 0.f;
  float xm2 = (lb >= 2) ? xz[(size_t)(lb - 2) * 4096 + d] : 0.f;
  float xm1 = (lb >= 1) ? xz[(size_t)(lb - 1) * 4096 + d] : 0.f;
#pragma unroll
  for (int j = 0; j < 8; ++j) {
    int l = lb + j;
    float cur = xz[(size_t)l * 4096 + d];
    float s = bias + w0 * xm3 + w1 * xm2 + w2 * xm1 + w3 * cur;
    s = s / (1.f + __expf(-s));
    xconv[(size_t)l * 2048 + d] = s;
    xconv_bf[(size_t)l * 2048 + d] = f32_bf16(s);
    xm3 = xm2; xm2 = xm1; xm1 = cur;
  }
}

// ---------------- selective scan (fused deltaA/deltaBu/y/gate) ----------------
template <int CTRL>
__device__ __forceinline__ float dpp_mov(float v) {
  int r = __builtin_amdgcn_update_dpp(0, __builtin_bit_cast(int, v), CTRL, 0xF, 0xF, true);
  return __builtin_bit_cast(float, r);
}

__global__ __launch_bounds__(256) void scan_kernel(const float* __restrict__ dt,
                                                   const float* __restrict__ xconv,
                                                   const float* __restrict__ proj,
                                                   const float* __restrict__ xz,
                                                   const float* __restrict__ A_log,
                                                   const float* __restrict__ Dskip,
                                                   unsigned short* __restrict__ ybf) {
  const int tid = threadIdx.x;
  const int wave = tid >> 6, lane = tid & 63;
  const int gw = blockIdx.x * 4 + wave;   // 0..511
  const int ch = lane >> 4, n = lane & 15;
  const int d = gw * 4 + ch;              // 0..2047
  const float A = -__expf(A_log[d * 16 + n]);
  const float Dv = Dskip[d];
  float h = 0.f;
  const int TC = 8;
  float pd[TC], px_[TC], pB[TC], pC[TC], pz[TC];

#define LOAD_CHUNK(tb)                                  \
  _Pragma("unroll") for (int j = 0; j < TC; ++j) {      \
    int t = (tb) + j;                                   \
    pd[j] = dt[(size_t)t * 2048 + d];                   \
    px_[j] = xconv[(size_t)t * 2048 + d];               \
    pB[j] = proj[t * 128 + 64 + n];                     \
    pC[j] = proj[t * 128 + 80 + n];                     \
    pz[j] = xz[(size_t)t * 4096 + 2048 + d];            \
  }

  LOAD_CHUNK(0)
  for (int tb = 0; tb < L_SEQ; tb += TC) {
    float cd[TC], cx[TC], cB[TC], cC[TC], cz[TC];
#pragma unroll
    for (int j = 0; j < TC; ++j) {
      cd[j] = pd[j]; cx[j] = px_[j]; cB[j] = pB[j]; cC[j] = pC[j]; cz[j] = pz[j];
    }
    if (tb + TC < L_SEQ) { LOAD_CHUNK(tb + TC) }
#pragma unroll
    for (int j = 0; j < TC; ++j) {
      float dtv = cd[j];
      float da = __expf(dtv * A);
      h = __builtin_fmaf(da, h, dtv * cB[j] * cx[j]);
      float p = h * cC[j];
      // 16-lane row reduce via DPP row_shr; total lands in lane 15 of each row
      p += dpp_mov<0x118>(p);  // shr 8
      p += dpp_mov<0x114>(p);  // shr 4
      p += dpp_mov<0x112>(p);  // shr 2
      p += dpp_mov<0x111>(p);  // shr 1
      float zv = cz[j];
      float yv = p + cx[j] * Dv;
      yv *= zv / (1.f + __expf(-zv));
      if (n == 15) ybf[(size_t)(tb + j) * 2048 + d] = f32_bf16(yv);
    }
  }
#undef LOAD_CHUNK
}

// ---------------- launcher ----------------
extern "C" void kernel_launch(void* const* d_in, const int* in_sizes, int n_in,
                              void* d_out, int out_size, void* d_ws, size_t ws_size,
                              hipStream_t stream) {
  const float* x      = (const float*)d_in[0];
  const float* ln_w   = (const float*)d_in[1];
  const float* ln_b   = (const float*)d_in[2];
  const float* W_in   = (const float*)d_in[3];
  const float* conv_w = (const float*)d_in[4];
  const float* conv_b = (const float*)d_in[5];
  const float* W_xproj= (const float*)d_in[6];
  const float* W_dt   = (const float*)d_in[7];
  const float* b_dt   = (const float*)d_in[8];
  const float* A_log  = (const float*)d_in[9];
  const float* Dskip  = (const float*)d_in[10];
  const float* W_out  = (const float*)d_in[11];
  float* out = (float*)d_out;

  char* ws = (char*)d_ws;
  size_t off = 0;
  auto alloc = [&](size_t bytes) {
    void* p = ws + off;
    off = (off + bytes + 255) & ~(size_t)255;
    return p;
  };
  unsigned short* xn_bf      = (unsigned short*)alloc((size_t)L_SEQ * D_MODEL * 2);
  unsigned short* W_in_bf    = (unsigned short*)alloc((size_t)2 * D_INNER * D_MODEL * 2);
  unsigned short* W_xprojp   = (unsigned short*)alloc((size_t)128 * D_INNER * 2);
  unsigned short* W_dt_bf    = (unsigned short*)alloc((size_t)D_INNER * DT_RANK * 2);
  unsigned short* W_out_bf   = (unsigned short*)alloc((size_t)D_MODEL * D_INNER * 2);
  float*          xz         = (float*)alloc((size_t)L_SEQ * 2 * D_INNER * 4);
  float*          xconv      = (float*)alloc((size_t)L_SEQ * D_INNER * 4);
  unsigned short* xconv_bf   = (unsigned short*)alloc((size_t)L_SEQ * D_INNER * 2);
  float*          proj       = (float*)alloc((size_t)L_SEQ * 128 * 4);
  unsigned short* dtlow_bf   = (unsigned short*)alloc((size_t)L_SEQ * DT_RANK * 2);
  float*          dtf        = (float*)alloc((size_t)L_SEQ * D_INNER * 4);
  unsigned short* y_bf       = (unsigned short*)alloc((size_t)L_SEQ * D_INNER * 2);

  // weight converts
  cvt_f32_bf16_4<<<(2 * D_INNER * D_MODEL / 4 + 255) / 256, 256, 0, stream>>>(W_in, W_in_bf, 2 * D_INNER * D_MODEL / 4);
  cvt_f32_bf16_4<<<(D_MODEL * D_INNER / 4 + 255) / 256, 256, 0, stream>>>(W_out, W_out_bf, D_MODEL * D_INNER / 4);
  cvt_f32_bf16_4<<<(D_INNER * DT_RANK / 4 + 255) / 256, 256, 0, stream>>>(W_dt, W_dt_bf, D_INNER * DT_RANK / 4);
  cvt_pad_xproj<<<128 * 2048 / 256, 256, 0, stream>>>(W_xproj, W_xprojp);

  // layernorm -> xn bf16
  ln_kernel<<<L_SEQ, 256, 0, stream>>>(x, ln_w, ln_b, xn_bf);

  // in_proj: xz = xn @ W_in^T   (M=2048, N=4096, K=1024)
  gemm_bt<0><<<dim3(4096 / BN, L_SEQ / BM), 256, 0, stream>>>(xn_bf, W_in_bf, xz, L_SEQ, 4096, 1024, nullptr);

  // depthwise conv + SiLU on xc = xz[:, :2048]
  conv_silu_kernel<<<dim3(D_INNER / 256, L_SEQ / 8), 256, 0, stream>>>(xz, conv_w, conv_b, xconv, xconv_bf);

  // x_proj: proj = xconv @ W_xprojp^T  (M=2048, N=128(pad), K=2048)
  gemm_bt<0><<<dim3(1, L_SEQ / BM), 256, 0, stream>>>(xconv_bf, W_xprojp, proj, L_SEQ, 128, D_INNER, nullptr);

  // dtlow -> bf16
  cvt_dtlow<<<L_SEQ * DT_RANK / 256, 256, 0, stream>>>(proj, dtlow_bf);

  // dt = softplus(dtlow @ W_dt^T + b_dt)  (M=2048, N=2048, K=64)
  gemm_bt<1><<<dim3(D_INNER / BN, L_SEQ / BM), 256, 0, stream>>>(dtlow_bf, W_dt_bf, dtf, L_SEQ, D_INNER, DT_RANK, b_dt);

  // fused selective scan + Dskip + SiLU(z) gating -> y bf16
  scan_kernel<<<128, 256, 0, stream>>>(dtf, xconv, proj, xz, A_log, Dskip, y_bf);

  // out_proj + residual  (M=2048, N=1024, K=2048)
  gemm_bt<2><<<dim3(D_MODEL / BN, L_SEQ / BM), 256, 0, stream>>>(y_bf, W_out_bf, out, L_SEQ, D_MODEL, D_INNER, x);
}

// Round 2
// 357.013 us; speedup vs baseline: 2.1075x; 2.1075x over previous
//
#include <hip/hip_runtime.h>

typedef __bf16 bf16x8 __attribute__((ext_vector_type(8)));
typedef float floatx4 __attribute__((ext_vector_type(4)));
typedef unsigned short ushort8 __attribute__((ext_vector_type(8)));

#define L_SEQ 2048
#define D_MODEL 1024
#define D_INNER 2048
#define D_STATE 16
#define DT_RANK 64

#define N_CHUNK 32
#define T_CHUNK 64  // L_SEQ / N_CHUNK

__device__ __forceinline__ unsigned short f32_bf16(float f) {
  unsigned int u = __builtin_bit_cast(unsigned int, f);
  u += 0x7fffu + ((u >> 16) & 1u);
  return (unsigned short)(u >> 16);
}

// ---------------- converts ----------------
__global__ __launch_bounds__(256) void cvt_f32_bf16_4(const float* __restrict__ in,
                                                      unsigned short* __restrict__ out, int n4) {
  int i = blockIdx.x * 256 + threadIdx.x;
  if (i < n4) {
    float4 v = ((const float4*)in)[i];
    ushort4 o;
    o.x = f32_bf16(v.x); o.y = f32_bf16(v.y); o.z = f32_bf16(v.z); o.w = f32_bf16(v.w);
    ((ushort4*)out)[i] = o;
  }
}

// W_xproj (96 x 2048) -> bf16 padded to (128 x 2048)
__global__ __launch_bounds__(256) void cvt_pad_xproj(const float* __restrict__ in,
                                                     unsigned short* __restrict__ out) {
  int i = blockIdx.x * 256 + threadIdx.x;  // < 128*2048
  int r = i >> 11, c = i & 2047;
  out[i] = (r < 96) ? f32_bf16(in[r * 2048 + c]) : (unsigned short)0;
}

// proj[:, :64] f32 (stride 128) -> dtlow bf16 [2048][64]
__global__ __launch_bounds__(256) void cvt_dtlow(const float* __restrict__ proj,
                                                 unsigned short* __restrict__ out) {
  int i = blockIdx.x * 256 + threadIdx.x;  // < 2048*64
  out[i] = f32_bf16(proj[(i >> 6) * 128 + (i & 63)]);
}

// ---------------- layernorm -> bf16 ----------------
__global__ __launch_bounds__(256) void ln_kernel(const float* __restrict__ x,
                                                 const float* __restrict__ w,
                                                 const float* __restrict__ b,
                                                 unsigned short* __restrict__ xn) {
  int row = blockIdx.x, tid = threadIdx.x;
  const float4 v = ((const float4*)(x + (size_t)row * D_MODEL))[tid];
  float s = v.x + v.y + v.z + v.w;
  float q = v.x * v.x + v.y * v.y + v.z * v.z + v.w * v.w;
#pragma unroll
  for (int o = 1; o < 64; o <<= 1) {
    s += __shfl_xor(s, o);
    q += __shfl_xor(q, o);
  }
  __shared__ float red[8];
  int wv = tid >> 6;
  if ((tid & 63) == 0) { red[wv] = s; red[4 + wv] = q; }
  __syncthreads();
  s = red[0] + red[1] + red[2] + red[3];
  q = red[4] + red[5] + red[6] + red[7];
  float mu = s * (1.f / 1024.f);
  float var = q * (1.f / 1024.f) - mu * mu;
  float rs = rsqrtf(var + 1e-5f);
  float4 wv4 = ((const float4*)w)[tid];
  float4 bv4 = ((const float4*)b)[tid];
  ushort4 o;
  o.x = f32_bf16((v.x - mu) * rs * wv4.x + bv4.x);
  o.y = f32_bf16((v.y - mu) * rs * wv4.y + bv4.y);
  o.z = f32_bf16((v.z - mu) * rs * wv4.z + bv4.z);
  o.w = f32_bf16((v.w - mu) * rs * wv4.w + bv4.w);
  ((ushort4*)(xn + (size_t)row * D_MODEL))[tid] = o;
}

// ---------------- GEMM: C[M][N] = A[M][K] * B[N][K]^T (bf16 in, f32 out) ----------------
// EPI: 0 = plain, 1 = softplus(v + bias[col]), 2 = v + extra[row*N+col]
#define BM 128
#define BN 128
#define BKK 32
#define LDW 40  // 32 + 8 pad (keeps 16B alignment, breaks bank conflicts)

template <int EPI>
__global__ __launch_bounds__(256) void gemm_bt(const unsigned short* __restrict__ A,
                                               const unsigned short* __restrict__ B,
                                               float* __restrict__ C, int M, int N, int K,
                                               const float* __restrict__ extra) {
  __shared__ unsigned short As[BM * LDW];
  __shared__ unsigned short Bs[BN * LDW];
  const int tid = threadIdx.x;
  const int lane = tid & 63, wave = tid >> 6;
  const int wr = wave >> 1, wc = wave & 1;
  const int rl = lane & 15, kg = lane >> 4;
  const int bx = blockIdx.x, by = blockIdx.y;
  const unsigned short* Ab = A + (size_t)by * BM * K;
  const unsigned short* Bb = B + (size_t)bx * BN * K;
  floatx4 acc[4][4] = {};
  for (int k0 = 0; k0 < K; k0 += BKK) {
#pragma unroll
    for (int c = tid; c < 512; c += 256) {
      int row = c >> 2, kp = (c & 3) << 3;
      *(ushort8*)&As[row * LDW + kp] = *(const ushort8*)(Ab + (size_t)row * K + k0 + kp);
    }
#pragma unroll
    for (int c = tid; c < 512; c += 256) {
      int row = c >> 2, kp = (c & 3) << 3;
      *(ushort8*)&Bs[row * LDW + kp] = *(const ushort8*)(Bb + (size_t)row * K + k0 + kp);
    }
    __syncthreads();
    bf16x8 af[4], bfr[4];
#pragma unroll
    for (int m = 0; m < 4; ++m)
      af[m] = *(const bf16x8*)&As[(wr * 64 + m * 16 + rl) * LDW + kg * 8];
#pragma unroll
    for (int n = 0; n < 4; ++n)
      bfr[n] = *(const bf16x8*)&Bs[(wc * 64 + n * 16 + rl) * LDW + kg * 8];
#pragma unroll
    for (int m = 0; m < 4; ++m)
#pragma unroll
      for (int n = 0; n < 4; ++n)
        acc[m][n] = __builtin_amdgcn_mfma_f32_16x16x32_bf16(af[m], bfr[n], acc[m][n], 0, 0, 0);
    __syncthreads();
  }
#pragma unroll
  for (int m = 0; m < 4; ++m) {
#pragma unroll
    for (int n = 0; n < 4; ++n) {
      int col = bx * BN + wc * 64 + n * 16 + rl;
#pragma unroll
      for (int j = 0; j < 4; ++j) {
        int rowg = by * BM + wr * 64 + m * 16 + kg * 4 + j;
        float v = acc[m][n][j];
        if (EPI == 1) {
          v += extra[col];
          v = (v > 20.f) ? v : log1pf(__expf(v));
        }
        if (EPI == 2) v += extra[(size_t)rowg * N + col];
        C[(size_t)rowg * N + col] = v;
      }
    }
  }
}

// ---------------- causal depthwise conv (k=4) + SiLU ----------------
__global__ __launch_bounds__(256) void conv_silu_kernel(const float* __restrict__ xz,
                                                        const float* __restrict__ cw,
                                                        const float* __restrict__ cb,
                                                        float* __restrict__ xconv,
                                                        unsigned short* __restrict__ xconv_bf) {
  int d = blockIdx.x * 256 + threadIdx.x;  // 0..2047
  int lb = blockIdx.y * 8;
  float w0 = cw[d * 4 + 0], w1 = cw[d * 4 + 1], w2 = cw[d * 4 + 2], w3 = cw[d * 4 + 3];
  float bias = cb[d];
  float xm3 = (lb >= 3) ? xz[(size_t)(lb - 3) * 4096 + d] : 0.f;
  float xm2 = (lb >= 2) ? xz[(size_t)(lb - 2) * 4096 + d] : 0.f;
  float xm1 = (lb >= 1) ? xz[(size_t)(lb - 1) * 4096 + d] : 0.f;
#pragma unroll
  for (int j = 0; j < 8; ++j) {
    int l = lb + j;
    float cur = xz[(size_t)l * 4096 + d];
    float s = bias + w0 * xm3 + w1 * xm2 + w2 * xm1 + w3 * cur;
    s = s / (1.f + __expf(-s));
    xconv[(size_t)l * 2048 + d] = s;
    xconv_bf[(size_t)l * 2048 + d] = f32_bf16(s);
    xm3 = xm2; xm2 = xm1; xm1 = cur;
  }
}

// ---------------- chunked selective scan ----------------
// lane mapping: lane = ch*16 + n; wave handles 4 channels (d = gw*4 + ch), 16 states each.

template <int CTRL>
__device__ __forceinline__ float dpp_mov(float v) {
  int r = __builtin_amdgcn_update_dpp(0, __builtin_bit_cast(int, v), CTRL, 0xF, 0xF, true);
  return __builtin_bit_cast(float, r);
}

// Pass A: per-chunk local scan from h=0; store P = prod(da) and hend.
__global__ __launch_bounds__(256) void scan_passA(const float* __restrict__ dt,
                                                  const float* __restrict__ xconv,
                                                  const float* __restrict__ proj,
                                                  const float* __restrict__ A_log,
                                                  float* __restrict__ Pprod,
                                                  float* __restrict__ hend) {
  const int tid = threadIdx.x;
  const int wave = tid >> 6, lane = tid & 63;
  const int gw = blockIdx.x * 4 + wave;   // 0..511
  const int ch = lane >> 4, n = lane & 15;
  const int d = gw * 4 + ch;              // 0..2047
  const int c = blockIdx.y;               // chunk
  const int t0 = c * T_CHUNK;
  const float A = -__expf(A_log[d * 16 + n]);
  float h = 0.f, P = 1.f;
  const int TC = 8;
  float pd[TC], px_[TC], pB[TC];
#pragma unroll
  for (int j = 0; j < TC; ++j) {
    int t = t0 + j;
    pd[j] = dt[(size_t)t * 2048 + d];
    px_[j] = xconv[(size_t)t * 2048 + d];
    pB[j] = proj[t * 128 + 64 + n];
  }
  for (int tb = t0; tb < t0 + T_CHUNK; tb += TC) {
    float cd[TC], cx[TC], cB[TC];
#pragma unroll
    for (int j = 0; j < TC; ++j) { cd[j] = pd[j]; cx[j] = px_[j]; cB[j] = pB[j]; }
    if (tb + TC < t0 + T_CHUNK) {
#pragma unroll
      for (int j = 0; j < TC; ++j) {
        int t = tb + TC + j;
        pd[j] = dt[(size_t)t * 2048 + d];
        px_[j] = xconv[(size_t)t * 2048 + d];
        pB[j] = proj[t * 128 + 64 + n];
      }
    }
#pragma unroll
    for (int j = 0; j < TC; ++j) {
      float dtv = cd[j];
      float da = __expf(dtv * A);
      P *= da;
      h = __builtin_fmaf(da, h, dtv * cB[j] * cx[j]);
    }
  }
  int idx = (c * 2048 + d) * 16 + n;
  Pprod[idx] = P;
  hend[idx] = h;
}

// Pass 2: sequential prefix over the 32 chunks for each of the 32768 states.
__global__ __launch_bounds__(256) void scan_prefix(const float* __restrict__ Pprod,
                                                   const float* __restrict__ hend,
                                                   float* __restrict__ hinit) {
  int i = blockIdx.x * 256 + threadIdx.x;  // 0..32767 = d*16+n
  float h = 0.f;
#pragma unroll
  for (int c = 0; c < N_CHUNK; ++c) {
    int idx = (c << 15) + i;
    hinit[idx] = h;
    h = __builtin_fmaf(Pprod[idx], h, hend[idx]);
  }
}

// Pass B: re-run local scan with true initial state; produce gated y (bf16).
__global__ __launch_bounds__(256) void scan_passB(const float* __restrict__ dt,
                                                  const float* __restrict__ xconv,
                                                  const float* __restrict__ proj,
                                                  const float* __restrict__ xz,
                                                  const float* __restrict__ A_log,
                                                  const float* __restrict__ Dskip,
                                                  const float* __restrict__ hinit,
                                                  unsigned short* __restrict__ ybf) {
  const int tid = threadIdx.x;
  const int wave = tid >> 6, lane = tid & 63;
  const int gw = blockIdx.x * 4 + wave;
  const int ch = lane >> 4, n = lane & 15;
  const int d = gw * 4 + ch;
  const int c = blockIdx.y;
  const int t0 = c * T_CHUNK;
  const float A = -__expf(A_log[d * 16 + n]);
  const float Dv = Dskip[d];
  float h = hinit[(c * 2048 + d) * 16 + n];
  const int TC = 8;
  float pd[TC], px_[TC], pB[TC], pC[TC], pz[TC];
#pragma unroll
  for (int j = 0; j < TC; ++j) {
    int t = t0 + j;
    pd[j] = dt[(size_t)t * 2048 + d];
    px_[j] = xconv[(size_t)t * 2048 + d];
    pB[j] = proj[t * 128 + 64 + n];
    pC[j] = proj[t * 128 + 80 + n];
    pz[j] = xz[(size_t)t * 4096 + 2048 + d];
  }
  for (int tb = t0; tb < t0 + T_CHUNK; tb += TC) {
    float cd[TC], cx[TC], cB[TC], cC[TC], cz[TC];
#pragma unroll
    for (int j = 0; j < TC; ++j) {
      cd[j] = pd[j]; cx[j] = px_[j]; cB[j] = pB[j]; cC[j] = pC[j]; cz[j] = pz[j];
    }
    if (tb + TC < t0 + T_CHUNK) {
#pragma unroll
      for (int j = 0; j < TC; ++j) {
        int t = tb + TC + j;
        pd[j] = dt[(size_t)t * 2048 + d];
        px_[j] = xconv[(size_t)t * 2048 + d];
        pB[j] = proj[t * 128 + 64 + n];
        pC[j] = proj[t * 128 + 80 + n];
        pz[j] = xz[(size_t)t * 4096 + 2048 + d];
      }
    }
#pragma unroll
    for (int j = 0; j < TC; ++j) {
      float dtv = cd[j];
      float da = __expf(dtv * A);
      h = __builtin_fmaf(da, h, dtv * cB[j] * cx[j]);
      float p = h * cC[j];
      // 16-lane row reduce via DPP row_shr; total lands in lane 15 of each row
      p += dpp_mov<0x118>(p);  // shr 8
      p += dpp_mov<0x114>(p);  // shr 4
      p += dpp_mov<0x112>(p);  // shr 2
      p += dpp_mov<0x111>(p);  // shr 1
      float zv = cz[j];
      float yv = p + cx[j] * Dv;
      yv *= zv / (1.f + __expf(-zv));
      if (n == 15) ybf[(size_t)(tb + j) * 2048 + d] = f32_bf16(yv);
    }
  }
}

// ---------------- launcher ----------------
extern "C" void kernel_launch(void* const* d_in, const int* in_sizes, int n_in,
                              void* d_out, int out_size, void* d_ws, size_t ws_size,
                              hipStream_t stream) {
  const float* x      = (const float*)d_in[0];
  const float* ln_w   = (const float*)d_in[1];
  const float* ln_b   = (const float*)d_in[2];
  const float* W_in   = (const float*)d_in[3];
  const float* conv_w = (const float*)d_in[4];
  const float* conv_b = (const float*)d_in[5];
  const float* W_xproj= (const float*)d_in[6];
  const float* W_dt   = (const float*)d_in[7];
  const float* b_dt   = (const float*)d_in[8];
  const float* A_log  = (const float*)d_in[9];
  const float* Dskip  = (const float*)d_in[10];
  const float* W_out  = (const float*)d_in[11];
  float* out = (float*)d_out;

  char* ws = (char*)d_ws;
  size_t off = 0;
  auto alloc = [&](size_t bytes) {
    void* p = ws + off;
    off = (off + bytes + 255) & ~(size_t)255;
    return p;
  };
  unsigned short* xn_bf      = (unsigned short*)alloc((size_t)L_SEQ * D_MODEL * 2);
  unsigned short* W_in_bf    = (unsigned short*)alloc((size_t)2 * D_INNER * D_MODEL * 2);
  unsigned short* W_xprojp   = (unsigned short*)alloc((size_t)128 * D_INNER * 2);
  unsigned short* W_dt_bf    = (unsigned short*)alloc((size_t)D_INNER * DT_RANK * 2);
  unsigned short* W_out_bf   = (unsigned short*)alloc((size_t)D_MODEL * D_INNER * 2);
  float*          xz         = (float*)alloc((size_t)L_SEQ * 2 * D_INNER * 4);
  float*          xconv      = (float*)alloc((size_t)L_SEQ * D_INNER * 4);
  unsigned short* xconv_bf   = (unsigned short*)alloc((size_t)L_SEQ * D_INNER * 2);
  float*          proj       = (float*)alloc((size_t)L_SEQ * 128 * 4);
  unsigned short* dtlow_bf   = (unsigned short*)alloc((size_t)L_SEQ * DT_RANK * 2);
  float*          dtf        = (float*)alloc((size_t)L_SEQ * D_INNER * 4);
  unsigned short* y_bf       = (unsigned short*)alloc((size_t)L_SEQ * D_INNER * 2);
  float*          Pprod      = (float*)alloc((size_t)N_CHUNK * D_INNER * D_STATE * 4);
  float*          hend       = (float*)alloc((size_t)N_CHUNK * D_INNER * D_STATE * 4);
  float*          hinit      = (float*)alloc((size_t)N_CHUNK * D_INNER * D_STATE * 4);

  // weight converts
  cvt_f32_bf16_4<<<(2 * D_INNER * D_MODEL / 4 + 255) / 256, 256, 0, stream>>>(W_in, W_in_bf, 2 * D_INNER * D_MODEL / 4);
  cvt_f32_bf16_4<<<(D_MODEL * D_INNER / 4 + 255) / 256, 256, 0, stream>>>(W_out, W_out_bf, D_MODEL * D_INNER / 4);
  cvt_f32_bf16_4<<<(D_INNER * DT_RANK / 4 + 255) / 256, 256, 0, stream>>>(W_dt, W_dt_bf, D_INNER * DT_RANK / 4);
  cvt_pad_xproj<<<128 * 2048 / 256, 256, 0, stream>>>(W_xproj, W_xprojp);

  // layernorm -> xn bf16
  ln_kernel<<<L_SEQ, 256, 0, stream>>>(x, ln_w, ln_b, xn_bf);

  // in_proj: xz = xn @ W_in^T   (M=2048, N=4096, K=1024)
  gemm_bt<0><<<dim3(4096 / BN, L_SEQ / BM), 256, 0, stream>>>(xn_bf, W_in_bf, xz, L_SEQ, 4096, 1024, nullptr);

  // depthwise conv + SiLU on xc = xz[:, :2048]
  conv_silu_kernel<<<dim3(D_INNER / 256, L_SEQ / 8), 256, 0, stream>>>(xz, conv_w, conv_b, xconv, xconv_bf);

  // x_proj: proj = xconv @ W_xprojp^T  (M=2048, N=128(pad), K=2048)
  gemm_bt<0><<<dim3(1, L_SEQ / BM), 256, 0, stream>>>(xconv_bf, W_xprojp, proj, L_SEQ, 128, D_INNER, nullptr);

  // dtlow -> bf16
  cvt_dtlow<<<L_SEQ * DT_RANK / 256, 256, 0, stream>>>(proj, dtlow_bf);

  // dt = softplus(dtlow @ W_dt^T + b_dt)  (M=2048, N=2048, K=64)
  gemm_bt<1><<<dim3(D_INNER / BN, L_SEQ / BM), 256, 0, stream>>>(dtlow_bf, W_dt_bf, dtf, L_SEQ, D_INNER, DT_RANK, b_dt);

  // chunked selective scan
  scan_passA<<<dim3(128, N_CHUNK), 256, 0, stream>>>(dtf, xconv, proj, A_log, Pprod, hend);
  scan_prefix<<<128, 256, 0, stream>>>(Pprod, hend, hinit);
  scan_passB<<<dim3(128, N_CHUNK), 256, 0, stream>>>(dtf, xconv, proj, xz, A_log, Dskip, hinit, y_bf);

  // out_proj + residual  (M=2048, N=1024, K=2048)
  gemm_bt<2><<<dim3(D_MODEL / BN, L_SEQ / BM), 256, 0, stream>>>(y_bf, W_out_bf, out, L_SEQ, D_MODEL, D_INNER, x);
}

// Round 3
// 297.576 us; speedup vs baseline: 2.5284x; 1.1997x over previous
//
#include <hip/hip_runtime.h>

typedef __bf16 bf16x8 __attribute__((ext_vector_type(8)));
typedef float floatx4 __attribute__((ext_vector_type(4)));
typedef unsigned short ushort8 __attribute__((ext_vector_type(8)));

#define L_SEQ 2048
#define D_MODEL 1024
#define D_INNER 2048
#define D_STATE 16
#define DT_RANK 64

#define N_CHUNK 64
#define T_CHUNK 32  // L_SEQ / N_CHUNK

__device__ __forceinline__ unsigned short f32_bf16(float f) {
  unsigned int u = __builtin_bit_cast(unsigned int, f);
  u += 0x7fffu + ((u >> 16) & 1u);
  return (unsigned short)(u >> 16);
}

// ---------------- converts ----------------
__global__ __launch_bounds__(256) void cvt_f32_bf16_4(const float* __restrict__ in,
                                                      unsigned short* __restrict__ out, int n4) {
  int i = blockIdx.x * 256 + threadIdx.x;
  if (i < n4) {
    float4 v = ((const float4*)in)[i];
    ushort4 o;
    o.x = f32_bf16(v.x); o.y = f32_bf16(v.y); o.z = f32_bf16(v.z); o.w = f32_bf16(v.w);
    ((ushort4*)out)[i] = o;
  }
}

// W_xproj (96 x 2048) -> bf16 padded to (128 x 2048)
__global__ __launch_bounds__(256) void cvt_pad_xproj(const float* __restrict__ in,
                                                     unsigned short* __restrict__ out) {
  int i = blockIdx.x * 256 + threadIdx.x;  // < 128*2048
  int r = i >> 11, c = i & 2047;
  out[i] = (r < 96) ? f32_bf16(in[r * 2048 + c]) : (unsigned short)0;
}

// proj[:, :64] f32 (stride 128) -> dtlow bf16 [2048][64]
__global__ __launch_bounds__(256) void cvt_dtlow(const float* __restrict__ proj,
                                                 unsigned short* __restrict__ out) {
  int i = blockIdx.x * 256 + threadIdx.x;  // < 2048*64
  out[i] = f32_bf16(proj[(i >> 6) * 128 + (i & 63)]);
}

// ---------------- layernorm -> bf16 ----------------
__global__ __launch_bounds__(256) void ln_kernel(const float* __restrict__ x,
                                                 const float* __restrict__ w,
                                                 const float* __restrict__ b,
                                                 unsigned short* __restrict__ xn) {
  int row = blockIdx.x, tid = threadIdx.x;
  const float4 v = ((const float4*)(x + (size_t)row * D_MODEL))[tid];
  float s = v.x + v.y + v.z + v.w;
  float q = v.x * v.x + v.y * v.y + v.z * v.z + v.w * v.w;
#pragma unroll
  for (int o = 1; o < 64; o <<= 1) {
    s += __shfl_xor(s, o);
    q += __shfl_xor(q, o);
  }
  __shared__ float red[8];
  int wv = tid >> 6;
  if ((tid & 63) == 0) { red[wv] = s; red[4 + wv] = q; }
  __syncthreads();
  s = red[0] + red[1] + red[2] + red[3];
  q = red[4] + red[5] + red[6] + red[7];
  float mu = s * (1.f / 1024.f);
  float var = q * (1.f / 1024.f) - mu * mu;
  float rs = rsqrtf(var + 1e-5f);
  float4 wv4 = ((const float4*)w)[tid];
  float4 bv4 = ((const float4*)b)[tid];
  ushort4 o;
  o.x = f32_bf16((v.x - mu) * rs * wv4.x + bv4.x);
  o.y = f32_bf16((v.y - mu) * rs * wv4.y + bv4.y);
  o.z = f32_bf16((v.z - mu) * rs * wv4.z + bv4.z);
  o.w = f32_bf16((v.w - mu) * rs * wv4.w + bv4.w);
  ((ushort4*)(xn + (size_t)row * D_MODEL))[tid] = o;
}

// ---------------- GEMM: C[M][N] = A[M][K] * B[N][K]^T (bf16 in, f32 out) ----------------
// EPI: 0 = plain, 1 = softplus(v + bias[col]), 2 = v + extra[row*N+col]
#define BM 128
#define BN 128
#define BKK 32
#define LDW 40  // 32 + 8 pad (keeps 16B alignment, breaks bank conflicts)

template <int EPI>
__global__ __launch_bounds__(256) void gemm_bt(const unsigned short* __restrict__ A,
                                               const unsigned short* __restrict__ B,
                                               float* __restrict__ C, int M, int N, int K,
                                               const float* __restrict__ extra) {
  __shared__ unsigned short As[BM * LDW];
  __shared__ unsigned short Bs[BN * LDW];
  const int tid = threadIdx.x;
  const int lane = tid & 63, wave = tid >> 6;
  const int wr = wave >> 1, wc = wave & 1;
  const int rl = lane & 15, kg = lane >> 4;
  const int bx = blockIdx.x, by = blockIdx.y;
  const unsigned short* Ab = A + (size_t)by * BM * K;
  const unsigned short* Bb = B + (size_t)bx * BN * K;
  floatx4 acc[4][4] = {};
  for (int k0 = 0; k0 < K; k0 += BKK) {
#pragma unroll
    for (int c = tid; c < 512; c += 256) {
      int row = c >> 2, kp = (c & 3) << 3;
      *(ushort8*)&As[row * LDW + kp] = *(const ushort8*)(Ab + (size_t)row * K + k0 + kp);
    }
#pragma unroll
    for (int c = tid; c < 512; c += 256) {
      int row = c >> 2, kp = (c & 3) << 3;
      *(ushort8*)&Bs[row * LDW + kp] = *(const ushort8*)(Bb + (size_t)row * K + k0 + kp);
    }
    __syncthreads();
    bf16x8 af[4], bfr[4];
#pragma unroll
    for (int m = 0; m < 4; ++m)
      af[m] = *(const bf16x8*)&As[(wr * 64 + m * 16 + rl) * LDW + kg * 8];
#pragma unroll
    for (int n = 0; n < 4; ++n)
      bfr[n] = *(const bf16x8*)&Bs[(wc * 64 + n * 16 + rl) * LDW + kg * 8];
#pragma unroll
    for (int m = 0; m < 4; ++m)
#pragma unroll
      for (int n = 0; n < 4; ++n)
        acc[m][n] = __builtin_amdgcn_mfma_f32_16x16x32_bf16(af[m], bfr[n], acc[m][n], 0, 0, 0);
    __syncthreads();
  }
#pragma unroll
  for (int m = 0; m < 4; ++m) {
#pragma unroll
    for (int n = 0; n < 4; ++n) {
      int col = bx * BN + wc * 64 + n * 16 + rl;
#pragma unroll
      for (int j = 0; j < 4; ++j) {
        int rowg = by * BM + wr * 64 + m * 16 + kg * 4 + j;
        float v = acc[m][n][j];
        if (EPI == 1) {
          v += extra[col];
          v = (v > 20.f) ? v : log1pf(__expf(v));
        }
        if (EPI == 2) v += extra[(size_t)rowg * N + col];
        C[(size_t)rowg * N + col] = v;
      }
    }
  }
}

// ---------------- causal depthwise conv (k=4) + SiLU ----------------
__global__ __launch_bounds__(256) void conv_silu_kernel(const float* __restrict__ xz,
                                                        const float* __restrict__ cw,
                                                        const float* __restrict__ cb,
                                                        float* __restrict__ xconv,
                                                        unsigned short* __restrict__ xconv_bf) {
  int d = blockIdx.x * 256 + threadIdx.x;  // 0..2047
  int lb = blockIdx.y * 8;
  float w0 = cw[d * 4 + 0], w1 = cw[d * 4 + 1], w2 = cw[d * 4 + 2], w3 = cw[d * 4 + 3];
  float bias = cb[d];
  float xm3 = (lb >= 3) ? xz[(size_t)(lb - 3) * 4096 + d] : 0.f;
  float xm2 = (lb >= 2) ? xz[(size_t)(lb - 2) * 4096 + d] : 0.f;
  float xm1 = (lb >= 1) ? xz[(size_t)(lb - 1) * 4096 + d] : 0.f;
#pragma unroll
  for (int j = 0; j < 8; ++j) {
    int l = lb + j;
    float cur = xz[(size_t)l * 4096 + d];
    float s = bias + w0 * xm3 + w1 * xm2 + w2 * xm1 + w3 * cur;
    s = s / (1.f + __expf(-s));
    xconv[(size_t)l * 2048 + d] = s;
    xconv_bf[(size_t)l * 2048 + d] = f32_bf16(s);
    xm3 = xm2; xm2 = xm1; xm1 = cur;
  }
}

// ---------------- chunked selective scan (lane owns channel d, 16 states in regs) ----------------
// Pass A: per-chunk local scan from h=0; store P = prod(da) and hend, laid out [c][d][n].
__global__ __launch_bounds__(256) void scan_passA(const float* __restrict__ dt,
                                                  const float* __restrict__ xconv,
                                                  const float* __restrict__ proj,
                                                  const float* __restrict__ A_log,
                                                  float* __restrict__ Pprod,
                                                  float* __restrict__ hend) {
  __shared__ float bc[T_CHUNK][32];  // [t][0:16]=B, [t][16:32]=C (C unused here but staged anyway)
  const int tid = threadIdx.x;
  const int c = blockIdx.y;
  const int t0 = c * T_CHUNK;
  {
    int t = tid >> 3, j = (tid & 7) * 4;
    *(float4*)&bc[t][j] = *(const float4*)&proj[(size_t)(t0 + t) * 128 + 64 + j];
  }
  __syncthreads();
  const int d = blockIdx.x * 256 + tid;
  float A[16];
#pragma unroll
  for (int q = 0; q < 4; ++q) {
    float4 al = ((const float4*)(A_log + (size_t)d * 16))[q];
    A[q * 4 + 0] = -__expf(al.x);
    A[q * 4 + 1] = -__expf(al.y);
    A[q * 4 + 2] = -__expf(al.z);
    A[q * 4 + 3] = -__expf(al.w);
  }
  float h[16], P[16];
#pragma unroll
  for (int n = 0; n < 16; ++n) { h[n] = 0.f; P[n] = 1.f; }

  const int TC = 8;
  float pd[TC], px[TC];
#pragma unroll
  for (int j = 0; j < TC; ++j) {
    pd[j] = dt[(size_t)(t0 + j) * 2048 + d];
    px[j] = xconv[(size_t)(t0 + j) * 2048 + d];
  }
  for (int tb = 0; tb < T_CHUNK; tb += TC) {
    float cd[TC], cx[TC];
#pragma unroll
    for (int j = 0; j < TC; ++j) { cd[j] = pd[j]; cx[j] = px[j]; }
    if (tb + TC < T_CHUNK) {
#pragma unroll
      for (int j = 0; j < TC; ++j) {
        pd[j] = dt[(size_t)(t0 + tb + TC + j) * 2048 + d];
        px[j] = xconv[(size_t)(t0 + tb + TC + j) * 2048 + d];
      }
    }
#pragma unroll
    for (int j = 0; j < TC; ++j) {
      int t = tb + j;
      float dtv = cd[j];
      float dtx = dtv * cx[j];
      float4 B0 = *(const float4*)&bc[t][0];
      float4 B1 = *(const float4*)&bc[t][4];
      float4 B2 = *(const float4*)&bc[t][8];
      float4 B3 = *(const float4*)&bc[t][12];
      float Bv[16] = {B0.x, B0.y, B0.z, B0.w, B1.x, B1.y, B1.z, B1.w,
                      B2.x, B2.y, B2.z, B2.w, B3.x, B3.y, B3.z, B3.w};
#pragma unroll
      for (int n = 0; n < 16; ++n) {
        float da = __expf(dtv * A[n]);
        P[n] *= da;
        h[n] = __builtin_fmaf(da, h[n], dtx * Bv[n]);
      }
    }
  }
  size_t base = ((size_t)c * 2048 + d) * 16;
#pragma unroll
  for (int q = 0; q < 4; ++q) {
    ((float4*)(Pprod + base))[q] = make_float4(P[q * 4], P[q * 4 + 1], P[q * 4 + 2], P[q * 4 + 3]);
    ((float4*)(hend + base))[q] = make_float4(h[q * 4], h[q * 4 + 1], h[q * 4 + 2], h[q * 4 + 3]);
  }
}

// Pass 2: sequential prefix over the chunks for each of the 32768 states.
__global__ __launch_bounds__(256) void scan_prefix(const float* __restrict__ Pprod,
                                                   const float* __restrict__ hend,
                                                   float* __restrict__ hinit) {
  int i = blockIdx.x * 256 + threadIdx.x;  // 0..32767 = d*16+n
  float h = 0.f;
  const int TC = 8;
  float pP[TC], pH[TC];
#pragma unroll
  for (int j = 0; j < TC; ++j) {
    pP[j] = Pprod[((size_t)j << 15) + i];
    pH[j] = hend[((size_t)j << 15) + i];
  }
  for (int cb = 0; cb < N_CHUNK; cb += TC) {
    float cP[TC], cH[TC];
#pragma unroll
    for (int j = 0; j < TC; ++j) { cP[j] = pP[j]; cH[j] = pH[j]; }
    if (cb + TC < N_CHUNK) {
#pragma unroll
      for (int j = 0; j < TC; ++j) {
        pP[j] = Pprod[((size_t)(cb + TC + j) << 15) + i];
        pH[j] = hend[((size_t)(cb + TC + j) << 15) + i];
      }
    }
#pragma unroll
    for (int j = 0; j < TC; ++j) {
      hinit[((size_t)(cb + j) << 15) + i] = h;
      h = __builtin_fmaf(cP[j], h, cH[j]);
    }
  }
}

// Pass B: local scan with true initial state; produce gated y (bf16).
__global__ __launch_bounds__(256) void scan_passB(const float* __restrict__ dt,
                                                  const float* __restrict__ xconv,
                                                  const float* __restrict__ proj,
                                                  const float* __restrict__ xz,
                                                  const float* __restrict__ A_log,
                                                  const float* __restrict__ Dskip,
                                                  const float* __restrict__ hinit,
                                                  unsigned short* __restrict__ ybf) {
  __shared__ float bc[T_CHUNK][32];  // [t][0:16]=B, [t][16:32]=C
  const int tid = threadIdx.x;
  const int c = blockIdx.y;
  const int t0 = c * T_CHUNK;
  {
    int t = tid >> 3, j = (tid & 7) * 4;
    *(float4*)&bc[t][j] = *(const float4*)&proj[(size_t)(t0 + t) * 128 + 64 + j];
  }
  __syncthreads();
  const int d = blockIdx.x * 256 + tid;
  float A[16];
#pragma unroll
  for (int q = 0; q < 4; ++q) {
    float4 al = ((const float4*)(A_log + (size_t)d * 16))[q];
    A[q * 4 + 0] = -__expf(al.x);
    A[q * 4 + 1] = -__expf(al.y);
    A[q * 4 + 2] = -__expf(al.z);
    A[q * 4 + 3] = -__expf(al.w);
  }
  const float Dv = Dskip[d];
  float h[16];
  {
    size_t base = ((size_t)c * 2048 + d) * 16;
#pragma unroll
    for (int q = 0; q < 4; ++q) {
      float4 hv = ((const float4*)(hinit + base))[q];
      h[q * 4 + 0] = hv.x; h[q * 4 + 1] = hv.y; h[q * 4 + 2] = hv.z; h[q * 4 + 3] = hv.w;
    }
  }
  const int TC = 8;
  float pd[TC], px[TC], pz[TC];
#pragma unroll
  for (int j = 0; j < TC; ++j) {
    pd[j] = dt[(size_t)(t0 + j) * 2048 + d];
    px[j] = xconv[(size_t)(t0 + j) * 2048 + d];
    pz[j] = xz[(size_t)(t0 + j) * 4096 + 2048 + d];
  }
  for (int tb = 0; tb < T_CHUNK; tb += TC) {
    float cd[TC], cx[TC], cz[TC];
#pragma unroll
    for (int j = 0; j < TC; ++j) { cd[j] = pd[j]; cx[j] = px[j]; cz[j] = pz[j]; }
    if (tb + TC < T_CHUNK) {
#pragma unroll
      for (int j = 0; j < TC; ++j) {
        pd[j] = dt[(size_t)(t0 + tb + TC + j) * 2048 + d];
        px[j] = xconv[(size_t)(t0 + tb + TC + j) * 2048 + d];
        pz[j] = xz[(size_t)(t0 + tb + TC + j) * 4096 + 2048 + d];
      }
    }
#pragma unroll
    for (int j = 0; j < TC; ++j) {
      int t = tb + j;
      float dtv = cd[j];
      float xv = cx[j];
      float dtx = dtv * xv;
      float4 B0 = *(const float4*)&bc[t][0];
      float4 B1 = *(const float4*)&bc[t][4];
      float4 B2 = *(const float4*)&bc[t][8];
      float4 B3 = *(const float4*)&bc[t][12];
      float4 C0 = *(const float4*)&bc[t][16];
      float4 C1 = *(const float4*)&bc[t][20];
      float4 C2 = *(const float4*)&bc[t][24];
      float4 C3 = *(const float4*)&bc[t][28];
      float Bv[16] = {B0.x, B0.y, B0.z, B0.w, B1.x, B1.y, B1.z, B1.w,
                      B2.x, B2.y, B2.z, B2.w, B3.x, B3.y, B3.z, B3.w};
      float Cv[16] = {C0.x, C0.y, C0.z, C0.w, C1.x, C1.y, C1.z, C1.w,
                      C2.x, C2.y, C2.z, C2.w, C3.x, C3.y, C3.z, C3.w};
      float y = 0.f;
#pragma unroll
      for (int n = 0; n < 16; ++n) {
        float da = __expf(dtv * A[n]);
        h[n] = __builtin_fmaf(da, h[n], dtx * Bv[n]);
        y = __builtin_fmaf(h[n], Cv[n], y);
      }
      float zv = cz[j];
      float yv = y + xv * Dv;
      yv *= zv / (1.f + __expf(-zv));
      ybf[(size_t)(t0 + t) * 2048 + d] = f32_bf16(yv);
    }
  }
}

// ---------------- launcher ----------------
extern "C" void kernel_launch(void* const* d_in, const int* in_sizes, int n_in,
                              void* d_out, int out_size, void* d_ws, size_t ws_size,
                              hipStream_t stream) {
  const float* x      = (const float*)d_in[0];
  const float* ln_w   = (const float*)d_in[1];
  const float* ln_b   = (const float*)d_in[2];
  const float* W_in   = (const float*)d_in[3];
  const float* conv_w = (const float*)d_in[4];
  const float* conv_b = (const float*)d_in[5];
  const float* W_xproj= (const float*)d_in[6];
  const float* W_dt   = (const float*)d_in[7];
  const float* b_dt   = (const float*)d_in[8];
  const float* A_log  = (const float*)d_in[9];
  const float* Dskip  = (const float*)d_in[10];
  const float* W_out  = (const float*)d_in[11];
  float* out = (float*)d_out;

  char* ws = (char*)d_ws;
  size_t off = 0;
  auto alloc = [&](size_t bytes) {
    void* p = ws + off;
    off = (off + bytes + 255) & ~(size_t)255;
    return p;
  };
  unsigned short* xn_bf      = (unsigned short*)alloc((size_t)L_SEQ * D_MODEL * 2);
  unsigned short* W_in_bf    = (unsigned short*)alloc((size_t)2 * D_INNER * D_MODEL * 2);
  unsigned short* W_xprojp   = (unsigned short*)alloc((size_t)128 * D_INNER * 2);
  unsigned short* W_dt_bf    = (unsigned short*)alloc((size_t)D_INNER * DT_RANK * 2);
  unsigned short* W_out_bf   = (unsigned short*)alloc((size_t)D_MODEL * D_INNER * 2);
  float*          xz         = (float*)alloc((size_t)L_SEQ * 2 * D_INNER * 4);
  float*          xconv      = (float*)alloc((size_t)L_SEQ * D_INNER * 4);
  unsigned short* xconv_bf   = (unsigned short*)alloc((size_t)L_SEQ * D_INNER * 2);
  float*          proj       = (float*)alloc((size_t)L_SEQ * 128 * 4);
  unsigned short* dtlow_bf   = (unsigned short*)alloc((size_t)L_SEQ * DT_RANK * 2);
  float*          dtf        = (float*)alloc((size_t)L_SEQ * D_INNER * 4);
  unsigned short* y_bf       = (unsigned short*)alloc((size_t)L_SEQ * D_INNER * 2);
  float*          Pprod      = (float*)alloc((size_t)N_CHUNK * D_INNER * D_STATE * 4);
  float*          hend       = (float*)alloc((size_t)N_CHUNK * D_INNER * D_STATE * 4);
  float*          hinit      = (float*)alloc((size_t)N_CHUNK * D_INNER * D_STATE * 4);

  // weight converts
  cvt_f32_bf16_4<<<(2 * D_INNER * D_MODEL / 4 + 255) / 256, 256, 0, stream>>>(W_in, W_in_bf, 2 * D_INNER * D_MODEL / 4);
  cvt_f32_bf16_4<<<(D_MODEL * D_INNER / 4 + 255) / 256, 256, 0, stream>>>(W_out, W_out_bf, D_MODEL * D_INNER / 4);
  cvt_f32_bf16_4<<<(D_INNER * DT_RANK / 4 + 255) / 256, 256, 0, stream>>>(W_dt, W_dt_bf, D_INNER * DT_RANK / 4);
  cvt_pad_xproj<<<128 * 2048 / 256, 256, 0, stream>>>(W_xproj, W_xprojp);

  // layernorm -> xn bf16
  ln_kernel<<<L_SEQ, 256, 0, stream>>>(x, ln_w, ln_b, xn_bf);

  // in_proj: xz = xn @ W_in^T   (M=2048, N=4096, K=1024)
  gemm_bt<0><<<dim3(4096 / BN, L_SEQ / BM), 256, 0, stream>>>(xn_bf, W_in_bf, xz, L_SEQ, 4096, 1024, nullptr);

  // depthwise conv + SiLU on xc = xz[:, :2048]
  conv_silu_kernel<<<dim3(D_INNER / 256, L_SEQ / 8), 256, 0, stream>>>(xz, conv_w, conv_b, xconv, xconv_bf);

  // x_proj: proj = xconv @ W_xprojp^T  (M=2048, N=128(pad), K=2048)
  gemm_bt<0><<<dim3(1, L_SEQ / BM), 256, 0, stream>>>(xconv_bf, W_xprojp, proj, L_SEQ, 128, D_INNER, nullptr);

  // dtlow -> bf16
  cvt_dtlow<<<L_SEQ * DT_RANK / 256, 256, 0, stream>>>(proj, dtlow_bf);

  // dt = softplus(dtlow @ W_dt^T + b_dt)  (M=2048, N=2048, K=64)
  gemm_bt<1><<<dim3(D_INNER / BN, L_SEQ / BM), 256, 0, stream>>>(dtlow_bf, W_dt_bf, dtf, L_SEQ, D_INNER, DT_RANK, b_dt);

  // chunked selective scan (transposed: lane owns a channel, 16 states in registers)
  scan_passA<<<dim3(D_INNER / 256, N_CHUNK), 256, 0, stream>>>(dtf, xconv, proj, A_log, Pprod, hend);
  scan_prefix<<<128, 256, 0, stream>>>(Pprod, hend, hinit);
  scan_passB<<<dim3(D_INNER / 256, N_CHUNK), 256, 0, stream>>>(dtf, xconv, proj, xz, A_log, Dskip, hinit, y_bf);

  // out_proj + residual  (M=2048, N=1024, K=2048)
  gemm_bt<2><<<dim3(D_MODEL / BN, L_SEQ / BM), 256, 0, stream>>>(y_bf, W_out_bf, out, L_SEQ, D_MODEL, D_INNER, x);
}

// Round 4
// 188.283 us; speedup vs baseline: 3.9961x; 1.5805x over previous
//
#include <hip/hip_runtime.h>

typedef __bf16 bf16x8 __attribute__((ext_vector_type(8)));
typedef float floatx4 __attribute__((ext_vector_type(4)));
typedef unsigned short ushort8 __attribute__((ext_vector_type(8)));

#define L_SEQ 2048
#define D_MODEL 1024
#define D_INNER 2048
#define D_STATE 16
#define DT_RANK 64

#define N_CHUNK 64
#define T_CHUNK 32  // L_SEQ / N_CHUNK

__device__ __forceinline__ unsigned short f32_bf16(float f) {
  unsigned int u = __builtin_bit_cast(unsigned int, f);
  u += 0x7fffu + ((u >> 16) & 1u);
  return (unsigned short)(u >> 16);
}

// async global->LDS, 16B per lane; lds base must be wave-uniform (m104)
__device__ __forceinline__ void stage16(const unsigned short* g, unsigned short* l) {
  __builtin_amdgcn_global_load_lds((const __attribute__((address_space(1))) unsigned int*)g,
                                   (__attribute__((address_space(3))) unsigned int*)l, 16, 0, 0);
}

// ---------------- converts ----------------
__global__ __launch_bounds__(256) void cvt_f32_bf16_4(const float* __restrict__ in,
                                                      unsigned short* __restrict__ out, int n4) {
  int i = blockIdx.x * 256 + threadIdx.x;
  if (i < n4) {
    float4 v = ((const float4*)in)[i];
    ushort4 o;
    o.x = f32_bf16(v.x); o.y = f32_bf16(v.y); o.z = f32_bf16(v.z); o.w = f32_bf16(v.w);
    ((ushort4*)out)[i] = o;
  }
}

// W_xproj (96 x 2048) -> bf16 padded to (128 x 2048)
__global__ __launch_bounds__(256) void cvt_pad_xproj(const float* __restrict__ in,
                                                     unsigned short* __restrict__ out) {
  int i = blockIdx.x * 256 + threadIdx.x;  // < 128*2048
  int r = i >> 11, c = i & 2047;
  out[i] = (r < 96) ? f32_bf16(in[r * 2048 + c]) : (unsigned short)0;
}

// proj[:, :64] f32 (stride 128) -> dtlow bf16 [2048][64]
__global__ __launch_bounds__(256) void cvt_dtlow(const float* __restrict__ proj,
                                                 unsigned short* __restrict__ out) {
  int i = blockIdx.x * 256 + threadIdx.x;  // < 2048*64
  out[i] = f32_bf16(proj[(i >> 6) * 128 + (i & 63)]);
}

// ---------------- layernorm -> bf16 ----------------
__global__ __launch_bounds__(256) void ln_kernel(const float* __restrict__ x,
                                                 const float* __restrict__ w,
                                                 const float* __restrict__ b,
                                                 unsigned short* __restrict__ xn) {
  int row = blockIdx.x, tid = threadIdx.x;
  const float4 v = ((const float4*)(x + (size_t)row * D_MODEL))[tid];
  float s = v.x + v.y + v.z + v.w;
  float q = v.x * v.x + v.y * v.y + v.z * v.z + v.w * v.w;
#pragma unroll
  for (int o = 1; o < 64; o <<= 1) {
    s += __shfl_xor(s, o);
    q += __shfl_xor(q, o);
  }
  __shared__ float red[8];
  int wv = tid >> 6;
  if ((tid & 63) == 0) { red[wv] = s; red[4 + wv] = q; }
  __syncthreads();
  s = red[0] + red[1] + red[2] + red[3];
  q = red[4] + red[5] + red[6] + red[7];
  float mu = s * (1.f / 1024.f);
  float var = q * (1.f / 1024.f) - mu * mu;
  float rs = rsqrtf(var + 1e-5f);
  float4 wv4 = ((const float4*)w)[tid];
  float4 bv4 = ((const float4*)b)[tid];
  ushort4 o;
  o.x = f32_bf16((v.x - mu) * rs * wv4.x + bv4.x);
  o.y = f32_bf16((v.y - mu) * rs * wv4.y + bv4.y);
  o.z = f32_bf16((v.z - mu) * rs * wv4.z + bv4.z);
  o.w = f32_bf16((v.w - mu) * rs * wv4.w + bv4.w);
  ((ushort4*)(xn + (size_t)row * D_MODEL))[tid] = o;
}

// ---------------- GEMM: C[M][N] = A[M][K] * B[N][K]^T (bf16 in, f32 out) ----------------
// global_load_lds staging (m97 structure), linear LDS [128][32].
// EPI: 0 = plain, 1 = softplus(v + bias[col]), 2 = v + extra[row*N+col]
// PARTIAL: write f32 partial tile at C + kz*M*N (no epilogue).
template <int EPI, bool PARTIAL>
__global__ __launch_bounds__(256) void gemm_bt(const unsigned short* __restrict__ A,
                                               const unsigned short* __restrict__ B,
                                               float* __restrict__ C, int M, int N, int K,
                                               int klen, const float* __restrict__ extra) {
  __shared__ unsigned short As[128 * 32];
  __shared__ unsigned short Bs[128 * 32];
  const int tid = threadIdx.x;
  const int lane = tid & 63, wave = tid >> 6;
  const int wr = wave >> 1, wc = wave & 1;
  const int rl = lane & 15, kg = lane >> 4;
  const int bx = blockIdx.x, by = blockIdx.y, kz = blockIdx.z;
  const unsigned short* Ab = A + (size_t)by * 128 * K;
  const unsigned short* Bb = B + (size_t)bx * 128 * K;
  // staging geometry: issue i covers rows i*64 + wave*16 + lane/4, 8 elems at col (lane&3)*8
  const int srow = wave * 16 + (lane >> 2);
  const int scol = (lane & 3) * 8;
  unsigned short* la0 = As + wave * 512;
  unsigned short* la1 = As + 2048 + wave * 512;
  unsigned short* lb0 = Bs + wave * 512;
  unsigned short* lb1 = Bs + 2048 + wave * 512;
  const int kbeg = kz * klen, kend = kbeg + klen;
  floatx4 acc[4][4] = {};
  for (int k0 = kbeg; k0 < kend; k0 += 32) {
    const unsigned short* ga = Ab + (size_t)srow * K + k0 + scol;
    const unsigned short* gb = Bb + (size_t)srow * K + k0 + scol;
    stage16(ga, la0);
    stage16(ga + (size_t)64 * K, la1);
    stage16(gb, lb0);
    stage16(gb + (size_t)64 * K, lb1);
    __syncthreads();  // drains vmcnt -> LDS tiles ready
    bf16x8 af[4], bfr[4];
#pragma unroll
    for (int m = 0; m < 4; ++m)
      af[m] = *(const bf16x8*)&As[(wr * 64 + m * 16 + rl) * 32 + kg * 8];
#pragma unroll
    for (int n = 0; n < 4; ++n)
      bfr[n] = *(const bf16x8*)&Bs[(wc * 64 + n * 16 + rl) * 32 + kg * 8];
#pragma unroll
    for (int m = 0; m < 4; ++m)
#pragma unroll
      for (int n = 0; n < 4; ++n)
        acc[m][n] = __builtin_amdgcn_mfma_f32_16x16x32_bf16(af[m], bfr[n], acc[m][n], 0, 0, 0);
    __syncthreads();  // before overwriting tiles
  }
  float* Cw = PARTIAL ? C + (size_t)kz * M * N : C;
#pragma unroll
  for (int m = 0; m < 4; ++m) {
#pragma unroll
    for (int n = 0; n < 4; ++n) {
      int col = bx * 128 + wc * 64 + n * 16 + rl;
#pragma unroll
      for (int j = 0; j < 4; ++j) {
        int rowg = by * 128 + wr * 64 + m * 16 + kg * 4 + j;
        float v = acc[m][n][j];
        if (!PARTIAL) {
          if (EPI == 1) {
            v += extra[col];
            v = (v > 20.f) ? v : log1pf(__expf(v));
          }
          if (EPI == 2) v += extra[(size_t)rowg * N + col];
        }
        Cw[(size_t)rowg * N + col] = v;
      }
    }
  }
}

// ---------------- split-K combine: out = sum_z part[z] (+ extra) ----------------
// EPI: 0 = plain, 2 = add extra elementwise
template <int NS, int EPI>
__global__ __launch_bounds__(256) void combine_k(const float* __restrict__ part,
                                                 float* __restrict__ out, int MN4,
                                                 const float* __restrict__ extra) {
  int i = blockIdx.x * 256 + threadIdx.x;
  if (i >= MN4) return;
  float4 s = ((const float4*)part)[i];
#pragma unroll
  for (int z = 1; z < NS; ++z) {
    float4 p = ((const float4*)(part + (size_t)z * MN4 * 4))[i];
    s.x += p.x; s.y += p.y; s.z += p.z; s.w += p.w;
  }
  if (EPI == 2) {
    float4 e = ((const float4*)extra)[i];
    s.x += e.x; s.y += e.y; s.z += e.z; s.w += e.w;
  }
  ((float4*)out)[i] = s;
}

// ---------------- causal depthwise conv (k=4) + SiLU ----------------
__global__ __launch_bounds__(256) void conv_silu_kernel(const float* __restrict__ xz,
                                                        const float* __restrict__ cw,
                                                        const float* __restrict__ cb,
                                                        float* __restrict__ xconv,
                                                        unsigned short* __restrict__ xconv_bf) {
  int d = blockIdx.x * 256 + threadIdx.x;  // 0..2047
  int lb = blockIdx.y * 8;
  float w0 = cw[d * 4 + 0], w1 = cw[d * 4 + 1], w2 = cw[d * 4 + 2], w3 = cw[d * 4 + 3];
  float bias = cb[d];
  float xm3 = (lb >= 3) ? xz[(size_t)(lb - 3) * 4096 + d] : 0.f;
  float xm2 = (lb >= 2) ? xz[(size_t)(lb - 2) * 4096 + d] : 0.f;
  float xm1 = (lb >= 1) ? xz[(size_t)(lb - 1) * 4096 + d] : 0.f;
#pragma unroll
  for (int j = 0; j < 8; ++j) {
    int l = lb + j;
    float cur = xz[(size_t)l * 4096 + d];
    float s = bias + w0 * xm3 + w1 * xm2 + w2 * xm1 + w3 * cur;
    s = s / (1.f + __expf(-s));
    xconv[(size_t)l * 2048 + d] = s;
    xconv_bf[(size_t)l * 2048 + d] = f32_bf16(s);
    xm3 = xm2; xm2 = xm1; xm1 = cur;
  }
}

// ---------------- chunked selective scan (lane owns channel d, 16 states in regs) ----------------
__global__ __launch_bounds__(256) void scan_passA(const float* __restrict__ dt,
                                                  const float* __restrict__ xconv,
                                                  const float* __restrict__ proj,
                                                  const float* __restrict__ A_log,
                                                  float* __restrict__ Pprod,
                                                  float* __restrict__ hend) {
  __shared__ float bc[T_CHUNK][32];
  const int tid = threadIdx.x;
  const int c = blockIdx.y;
  const int t0 = c * T_CHUNK;
  {
    int t = tid >> 3, j = (tid & 7) * 4;
    *(float4*)&bc[t][j] = *(const float4*)&proj[(size_t)(t0 + t) * 128 + 64 + j];
  }
  __syncthreads();
  const int d = blockIdx.x * 256 + tid;
  float A[16];
#pragma unroll
  for (int q = 0; q < 4; ++q) {
    float4 al = ((const float4*)(A_log + (size_t)d * 16))[q];
    A[q * 4 + 0] = -__expf(al.x);
    A[q * 4 + 1] = -__expf(al.y);
    A[q * 4 + 2] = -__expf(al.z);
    A[q * 4 + 3] = -__expf(al.w);
  }
  float h[16], P[16];
#pragma unroll
  for (int n = 0; n < 16; ++n) { h[n] = 0.f; P[n] = 1.f; }

  const int TC = 8;
  float pd[TC], px[TC];
#pragma unroll
  for (int j = 0; j < TC; ++j) {
    pd[j] = dt[(size_t)(t0 + j) * 2048 + d];
    px[j] = xconv[(size_t)(t0 + j) * 2048 + d];
  }
  for (int tb = 0; tb < T_CHUNK; tb += TC) {
    float cd[TC], cx[TC];
#pragma unroll
    for (int j = 0; j < TC; ++j) { cd[j] = pd[j]; cx[j] = px[j]; }
    if (tb + TC < T_CHUNK) {
#pragma unroll
      for (int j = 0; j < TC; ++j) {
        pd[j] = dt[(size_t)(t0 + tb + TC + j) * 2048 + d];
        px[j] = xconv[(size_t)(t0 + tb + TC + j) * 2048 + d];
      }
    }
#pragma unroll
    for (int j = 0; j < TC; ++j) {
      int t = tb + j;
      float dtv = cd[j];
      float dtx = dtv * cx[j];
      float4 B0 = *(const float4*)&bc[t][0];
      float4 B1 = *(const float4*)&bc[t][4];
      float4 B2 = *(const float4*)&bc[t][8];
      float4 B3 = *(const float4*)&bc[t][12];
      float Bv[16] = {B0.x, B0.y, B0.z, B0.w, B1.x, B1.y, B1.z, B1.w,
                      B2.x, B2.y, B2.z, B2.w, B3.x, B3.y, B3.z, B3.w};
#pragma unroll
      for (int n = 0; n < 16; ++n) {
        float da = __expf(dtv * A[n]);
        P[n] *= da;
        h[n] = __builtin_fmaf(da, h[n], dtx * Bv[n]);
      }
    }
  }
  size_t base = ((size_t)c * 2048 + d) * 16;
#pragma unroll
  for (int q = 0; q < 4; ++q) {
    ((float4*)(Pprod + base))[q] = make_float4(P[q * 4], P[q * 4 + 1], P[q * 4 + 2], P[q * 4 + 3]);
    ((float4*)(hend + base))[q] = make_float4(h[q * 4], h[q * 4 + 1], h[q * 4 + 2], h[q * 4 + 3]);
  }
}

__global__ __launch_bounds__(256) void scan_prefix(const float* __restrict__ Pprod,
                                                   const float* __restrict__ hend,
                                                   float* __restrict__ hinit) {
  int i = blockIdx.x * 256 + threadIdx.x;  // 0..32767 = d*16+n
  float h = 0.f;
  const int TC = 8;
  float pP[TC], pH[TC];
#pragma unroll
  for (int j = 0; j < TC; ++j) {
    pP[j] = Pprod[((size_t)j << 15) + i];
    pH[j] = hend[((size_t)j << 15) + i];
  }
  for (int cb = 0; cb < N_CHUNK; cb += TC) {
    float cP[TC], cH[TC];
#pragma unroll
    for (int j = 0; j < TC; ++j) { cP[j] = pP[j]; cH[j] = pH[j]; }
    if (cb + TC < N_CHUNK) {
#pragma unroll
      for (int j = 0; j < TC; ++j) {
        pP[j] = Pprod[((size_t)(cb + TC + j) << 15) + i];
        pH[j] = hend[((size_t)(cb + TC + j) << 15) + i];
      }
    }
#pragma unroll
    for (int j = 0; j < TC; ++j) {
      hinit[((size_t)(cb + j) << 15) + i] = h;
      h = __builtin_fmaf(cP[j], h, cH[j]);
    }
  }
}

__global__ __launch_bounds__(256) void scan_passB(const float* __restrict__ dt,
                                                  const float* __restrict__ xconv,
                                                  const float* __restrict__ proj,
                                                  const float* __restrict__ xz,
                                                  const float* __restrict__ A_log,
                                                  const float* __restrict__ Dskip,
                                                  const float* __restrict__ hinit,
                                                  unsigned short* __restrict__ ybf) {
  __shared__ float bc[T_CHUNK][32];
  const int tid = threadIdx.x;
  const int c = blockIdx.y;
  const int t0 = c * T_CHUNK;
  {
    int t = tid >> 3, j = (tid & 7) * 4;
    *(float4*)&bc[t][j] = *(const float4*)&proj[(size_t)(t0 + t) * 128 + 64 + j];
  }
  __syncthreads();
  const int d = blockIdx.x * 256 + tid;
  float A[16];
#pragma unroll
  for (int q = 0; q < 4; ++q) {
    float4 al = ((const float4*)(A_log + (size_t)d * 16))[q];
    A[q * 4 + 0] = -__expf(al.x);
    A[q * 4 + 1] = -__expf(al.y);
    A[q * 4 + 2] = -__expf(al.z);
    A[q * 4 + 3] = -__expf(al.w);
  }
  const float Dv = Dskip[d];
  float h[16];
  {
    size_t base = ((size_t)c * 2048 + d) * 16;
#pragma unroll
    for (int q = 0; q < 4; ++q) {
      float4 hv = ((const float4*)(hinit + base))[q];
      h[q * 4 + 0] = hv.x; h[q * 4 + 1] = hv.y; h[q * 4 + 2] = hv.z; h[q * 4 + 3] = hv.w;
    }
  }
  const int TC = 8;
  float pd[TC], px[TC], pz[TC];
#pragma unroll
  for (int j = 0; j < TC; ++j) {
    pd[j] = dt[(size_t)(t0 + j) * 2048 + d];
    px[j] = xconv[(size_t)(t0 + j) * 2048 + d];
    pz[j] = xz[(size_t)(t0 + j) * 4096 + 2048 + d];
  }
  for (int tb = 0; tb < T_CHUNK; tb += TC) {
    float cd[TC], cx[TC], cz[TC];
#pragma unroll
    for (int j = 0; j < TC; ++j) { cd[j] = pd[j]; cx[j] = px[j]; cz[j] = pz[j]; }
    if (tb + TC < T_CHUNK) {
#pragma unroll
      for (int j = 0; j < TC; ++j) {
        pd[j] = dt[(size_t)(t0 + tb + TC + j) * 2048 + d];
        px[j] = xconv[(size_t)(t0 + tb + TC + j) * 2048 + d];
        pz[j] = xz[(size_t)(t0 + tb + TC + j) * 4096 + 2048 + d];
      }
    }
#pragma unroll
    for (int j = 0; j < TC; ++j) {
      int t = tb + j;
      float dtv = cd[j];
      float xv = cx[j];
      float dtx = dtv * xv;
      float4 B0 = *(const float4*)&bc[t][0];
      float4 B1 = *(const float4*)&bc[t][4];
      float4 B2 = *(const float4*)&bc[t][8];
      float4 B3 = *(const float4*)&bc[t][12];
      float4 C0 = *(const float4*)&bc[t][16];
      float4 C1 = *(const float4*)&bc[t][20];
      float4 C2 = *(const float4*)&bc[t][24];
      float4 C3 = *(const float4*)&bc[t][28];
      float Bv[16] = {B0.x, B0.y, B0.z, B0.w, B1.x, B1.y, B1.z, B1.w,
                      B2.x, B2.y, B2.z, B2.w, B3.x, B3.y, B3.z, B3.w};
      float Cv[16] = {C0.x, C0.y, C0.z, C0.w, C1.x, C1.y, C1.z, C1.w,
                      C2.x, C2.y, C2.z, C2.w, C3.x, C3.y, C3.z, C3.w};
      float y = 0.f;
#pragma unroll
      for (int n = 0; n < 16; ++n) {
        float da = __expf(dtv * A[n]);
        h[n] = __builtin_fmaf(da, h[n], dtx * Bv[n]);
        y = __builtin_fmaf(h[n], Cv[n], y);
      }
      float zv = cz[j];
      float yv = y + xv * Dv;
      yv *= zv / (1.f + __expf(-zv));
      ybf[(size_t)(t0 + t) * 2048 + d] = f32_bf16(yv);
    }
  }
}

// ---------------- launcher ----------------
extern "C" void kernel_launch(void* const* d_in, const int* in_sizes, int n_in,
                              void* d_out, int out_size, void* d_ws, size_t ws_size,
                              hipStream_t stream) {
  const float* x      = (const float*)d_in[0];
  const float* ln_w   = (const float*)d_in[1];
  const float* ln_b   = (const float*)d_in[2];
  const float* W_in   = (const float*)d_in[3];
  const float* conv_w = (const float*)d_in[4];
  const float* conv_b = (const float*)d_in[5];
  const float* W_xproj= (const float*)d_in[6];
  const float* W_dt   = (const float*)d_in[7];
  const float* b_dt   = (const float*)d_in[8];
  const float* A_log  = (const float*)d_in[9];
  const float* Dskip  = (const float*)d_in[10];
  const float* W_out  = (const float*)d_in[11];
  float* out = (float*)d_out;

  char* ws = (char*)d_ws;
  size_t off = 0;
  auto alloc = [&](size_t bytes) {
    void* p = ws + off;
    off = (off + bytes + 255) & ~(size_t)255;
    return p;
  };
  unsigned short* xn_bf      = (unsigned short*)alloc((size_t)L_SEQ * D_MODEL * 2);
  unsigned short* W_in_bf    = (unsigned short*)alloc((size_t)2 * D_INNER * D_MODEL * 2);
  unsigned short* W_xprojp   = (unsigned short*)alloc((size_t)128 * D_INNER * 2);
  unsigned short* W_dt_bf    = (unsigned short*)alloc((size_t)D_INNER * DT_RANK * 2);
  unsigned short* W_out_bf   = (unsigned short*)alloc((size_t)D_MODEL * D_INNER * 2);
  float*          xz         = (float*)alloc((size_t)L_SEQ * 2 * D_INNER * 4);
  float*          xconv      = (float*)alloc((size_t)L_SEQ * D_INNER * 4);
  unsigned short* xconv_bf   = (unsigned short*)alloc((size_t)L_SEQ * D_INNER * 2);
  float*          proj       = (float*)alloc((size_t)L_SEQ * 128 * 4);
  unsigned short* dtlow_bf   = (unsigned short*)alloc((size_t)L_SEQ * DT_RANK * 2);
  float*          dtf        = (float*)alloc((size_t)L_SEQ * D_INNER * 4);
  unsigned short* y_bf       = (unsigned short*)alloc((size_t)L_SEQ * D_INNER * 2);
  float*          Pprod      = (float*)alloc((size_t)N_CHUNK * D_INNER * D_STATE * 4);
  float*          hend       = (float*)alloc((size_t)N_CHUNK * D_INNER * D_STATE * 4);
  float*          hinit      = (float*)alloc((size_t)N_CHUNK * D_INNER * D_STATE * 4);
  float*          part_xp    = (float*)alloc((size_t)16 * L_SEQ * 128 * 4);     // 16 MB
  float*          part_out   = (float*)alloc((size_t)4 * L_SEQ * D_MODEL * 4);  // 32 MB

  // weight converts
  cvt_f32_bf16_4<<<(2 * D_INNER * D_MODEL / 4 + 255) / 256, 256, 0, stream>>>(W_in, W_in_bf, 2 * D_INNER * D_MODEL / 4);
  cvt_f32_bf16_4<<<(D_MODEL * D_INNER / 4 + 255) / 256, 256, 0, stream>>>(W_out, W_out_bf, D_MODEL * D_INNER / 4);
  cvt_f32_bf16_4<<<(D_INNER * DT_RANK / 4 + 255) / 256, 256, 0, stream>>>(W_dt, W_dt_bf, D_INNER * DT_RANK / 4);
  cvt_pad_xproj<<<128 * 2048 / 256, 256, 0, stream>>>(W_xproj, W_xprojp);

  // layernorm -> xn bf16
  ln_kernel<<<L_SEQ, 256, 0, stream>>>(x, ln_w, ln_b, xn_bf);

  // in_proj: xz = xn @ W_in^T   (M=2048, N=4096, K=1024)
  gemm_bt<0, false><<<dim3(32, 16, 1), 256, 0, stream>>>(xn_bf, W_in_bf, xz, L_SEQ, 4096, 1024, 1024, nullptr);

  // depthwise conv + SiLU on xc = xz[:, :2048]
  conv_silu_kernel<<<dim3(D_INNER / 256, L_SEQ / 8), 256, 0, stream>>>(xz, conv_w, conv_b, xconv, xconv_bf);

  // x_proj: proj = xconv @ W_xprojp^T  (M=2048, N=128(pad), K=2048), split-K 16
  gemm_bt<0, true><<<dim3(1, 16, 16), 256, 0, stream>>>(xconv_bf, W_xprojp, part_xp, L_SEQ, 128, 2048, 128, nullptr);
  combine_k<16, 0><<<(L_SEQ * 128 / 4) / 256, 256, 0, stream>>>(part_xp, proj, L_SEQ * 128 / 4, nullptr);

  // dtlow -> bf16
  cvt_dtlow<<<L_SEQ * DT_RANK / 256, 256, 0, stream>>>(proj, dtlow_bf);

  // dt = softplus(dtlow @ W_dt^T + b_dt)  (M=2048, N=2048, K=64)
  gemm_bt<1, false><<<dim3(16, 16, 1), 256, 0, stream>>>(dtlow_bf, W_dt_bf, dtf, L_SEQ, 2048, 64, 64, b_dt);

  // chunked selective scan (transposed: lane owns a channel, 16 states in registers)
  scan_passA<<<dim3(D_INNER / 256, N_CHUNK), 256, 0, stream>>>(dtf, xconv, proj, A_log, Pprod, hend);
  scan_prefix<<<128, 256, 0, stream>>>(Pprod, hend, hinit);
  scan_passB<<<dim3(D_INNER / 256, N_CHUNK), 256, 0, stream>>>(dtf, xconv, proj, xz, A_log, Dskip, hinit, y_bf);

  // out_proj (M=2048, N=1024, K=2048), split-K 4; combine adds residual
  gemm_bt<0, true><<<dim3(8, 16, 4), 256, 0, stream>>>(y_bf, W_out_bf, part_out, L_SEQ, 1024, 2048, 512, nullptr);
  combine_k<4, 2><<<(L_SEQ * D_MODEL / 4) / 256, 256, 0, stream>>>(part_out, out, L_SEQ * D_MODEL / 4, x);
}

// Round 5
// 178.993 us; speedup vs baseline: 4.2035x; 1.0519x over previous
//
#include <hip/hip_runtime.h>

typedef __bf16 bf16x8 __attribute__((ext_vector_type(8)));
typedef float floatx4 __attribute__((ext_vector_type(4)));
typedef unsigned short ushort8 __attribute__((ext_vector_type(8)));

#define L_SEQ 2048
#define D_MODEL 1024
#define D_INNER 2048
#define D_STATE 16
#define DT_RANK 64

#define N_CHUNK 64
#define T_CHUNK 32  // L_SEQ / N_CHUNK

__device__ __forceinline__ unsigned short f32_bf16(float f) {
  unsigned int u = __builtin_bit_cast(unsigned int, f);
  u += 0x7fffu + ((u >> 16) & 1u);
  return (unsigned short)(u >> 16);
}
__device__ __forceinline__ float bf16_f32(unsigned short u) {
  return __builtin_bit_cast(float, (unsigned int)u << 16);
}

// async global->LDS, 16B per lane; lds base must be wave-uniform (m104)
__device__ __forceinline__ void stage16(const unsigned short* g, unsigned short* l) {
  __builtin_amdgcn_global_load_lds((const __attribute__((address_space(1))) unsigned int*)g,
                                   (__attribute__((address_space(3))) unsigned int*)l, 16, 0, 0);
}

// ---------------- converts ----------------
__global__ __launch_bounds__(256) void cvt_f32_bf16_4(const float* __restrict__ in,
                                                      unsigned short* __restrict__ out, int n4) {
  int i = blockIdx.x * 256 + threadIdx.x;
  if (i < n4) {
    float4 v = ((const float4*)in)[i];
    ushort4 o;
    o.x = f32_bf16(v.x); o.y = f32_bf16(v.y); o.z = f32_bf16(v.z); o.w = f32_bf16(v.w);
    ((ushort4*)out)[i] = o;
  }
}

// W_xproj (96 x 2048) -> bf16 padded to (128 x 2048)
__global__ __launch_bounds__(256) void cvt_pad_xproj(const float* __restrict__ in,
                                                     unsigned short* __restrict__ out) {
  int i = blockIdx.x * 256 + threadIdx.x;  // < 128*2048
  int r = i >> 11, c = i & 2047;
  out[i] = (r < 96) ? f32_bf16(in[r * 2048 + c]) : (unsigned short)0;
}

// ---------------- layernorm -> bf16 ----------------
__global__ __launch_bounds__(256) void ln_kernel(const float* __restrict__ x,
                                                 const float* __restrict__ w,
                                                 const float* __restrict__ b,
                                                 unsigned short* __restrict__ xn) {
  int row = blockIdx.x, tid = threadIdx.x;
  const float4 v = ((const float4*)(x + (size_t)row * D_MODEL))[tid];
  float s = v.x + v.y + v.z + v.w;
  float q = v.x * v.x + v.y * v.y + v.z * v.z + v.w * v.w;
#pragma unroll
  for (int o = 1; o < 64; o <<= 1) {
    s += __shfl_xor(s, o);
    q += __shfl_xor(q, o);
  }
  __shared__ float red[8];
  int wv = tid >> 6;
  if ((tid & 63) == 0) { red[wv] = s; red[4 + wv] = q; }
  __syncthreads();
  s = red[0] + red[1] + red[2] + red[3];
  q = red[4] + red[5] + red[6] + red[7];
  float mu = s * (1.f / 1024.f);
  float var = q * (1.f / 1024.f) - mu * mu;
  float rs = rsqrtf(var + 1e-5f);
  float4 wv4 = ((const float4*)w)[tid];
  float4 bv4 = ((const float4*)b)[tid];
  ushort4 o;
  o.x = f32_bf16((v.x - mu) * rs * wv4.x + bv4.x);
  o.y = f32_bf16((v.y - mu) * rs * wv4.y + bv4.y);
  o.z = f32_bf16((v.z - mu) * rs * wv4.z + bv4.z);
  o.w = f32_bf16((v.w - mu) * rs * wv4.w + bv4.w);
  ((ushort4*)(xn + (size_t)row * D_MODEL))[tid] = o;
}

// ---------------- GEMM: C[M][N] = A[M][K] * B[N][K]^T (bf16 in) ----------------
// global_load_lds staging (m97 structure), linear LDS [128][32].
// EPI: 0 = plain, 1 = softplus(v + bias[col])
// PARTIAL: write f32 partial tile at C + kz*M*N (no epilogue). OBF: write bf16.
template <int EPI, bool PARTIAL, bool OBF>
__global__ __launch_bounds__(256) void gemm_bt(const unsigned short* __restrict__ A,
                                               const unsigned short* __restrict__ B,
                                               void* __restrict__ Cout, int M, int N, int K,
                                               int klen, const float* __restrict__ extra) {
  __shared__ unsigned short As[128 * 32];
  __shared__ unsigned short Bs[128 * 32];
  const int tid = threadIdx.x;
  const int lane = tid & 63, wave = tid >> 6;
  const int wr = wave >> 1, wc = wave & 1;
  const int rl = lane & 15, kg = lane >> 4;
  const int bx = blockIdx.x, by = blockIdx.y, kz = blockIdx.z;
  const unsigned short* Ab = A + (size_t)by * 128 * K;
  const unsigned short* Bb = B + (size_t)bx * 128 * K;
  const int srow = wave * 16 + (lane >> 2);
  const int scol = (lane & 3) * 8;
  unsigned short* la0 = As + wave * 512;
  unsigned short* la1 = As + 2048 + wave * 512;
  unsigned short* lb0 = Bs + wave * 512;
  unsigned short* lb1 = Bs + 2048 + wave * 512;
  const int kbeg = kz * klen, kend = kbeg + klen;
  floatx4 acc[4][4] = {};
  for (int k0 = kbeg; k0 < kend; k0 += 32) {
    const unsigned short* ga = Ab + (size_t)srow * K + k0 + scol;
    const unsigned short* gb = Bb + (size_t)srow * K + k0 + scol;
    stage16(ga, la0);
    stage16(ga + (size_t)64 * K, la1);
    stage16(gb, lb0);
    stage16(gb + (size_t)64 * K, lb1);
    __syncthreads();  // drains vmcnt -> LDS tiles ready
    bf16x8 af[4], bfr[4];
#pragma unroll
    for (int m = 0; m < 4; ++m)
      af[m] = *(const bf16x8*)&As[(wr * 64 + m * 16 + rl) * 32 + kg * 8];
#pragma unroll
    for (int n = 0; n < 4; ++n)
      bfr[n] = *(const bf16x8*)&Bs[(wc * 64 + n * 16 + rl) * 32 + kg * 8];
#pragma unroll
    for (int m = 0; m < 4; ++m)
#pragma unroll
      for (int n = 0; n < 4; ++n)
        acc[m][n] = __builtin_amdgcn_mfma_f32_16x16x32_bf16(af[m], bfr[n], acc[m][n], 0, 0, 0);
    __syncthreads();  // before overwriting tiles
  }
  float* Cf = PARTIAL ? (float*)Cout + (size_t)kz * M * N : (float*)Cout;
  unsigned short* Cb = (unsigned short*)Cout;
#pragma unroll
  for (int m = 0; m < 4; ++m) {
#pragma unroll
    for (int n = 0; n < 4; ++n) {
      int col = bx * 128 + wc * 64 + n * 16 + rl;
#pragma unroll
      for (int j = 0; j < 4; ++j) {
        int rowg = by * 128 + wr * 64 + m * 16 + kg * 4 + j;
        float v = acc[m][n][j];
        if (!PARTIAL && EPI == 1) {
          v += extra[col];
          v = (v > 20.f) ? v : log1pf(__expf(v));
        }
        if (OBF)
          Cb[(size_t)rowg * N + col] = f32_bf16(v);
        else
          Cf[(size_t)rowg * N + col] = v;
      }
    }
  }
}

// ---------------- split-K combines ----------------
// out-proj: out = sum_z part[z] + residual
__global__ __launch_bounds__(256) void combine_out(const float* __restrict__ part,
                                                   float* __restrict__ out, int MN4,
                                                   const float* __restrict__ extra) {
  int i = blockIdx.x * 256 + threadIdx.x;
  if (i >= MN4) return;
  float4 s = ((const float4*)part)[i];
#pragma unroll
  for (int z = 1; z < 4; ++z) {
    float4 p = ((const float4*)(part + (size_t)z * MN4 * 4))[i];
    s.x += p.x; s.y += p.y; s.z += p.z; s.w += p.w;
  }
  float4 e = ((const float4*)extra)[i];
  s.x += e.x; s.y += e.y; s.z += e.z; s.w += e.w;
  ((float4*)out)[i] = s;
}

// x-proj: proj = sum_z part[z]; also emit dtlow bf16 for cols [0,64)
__global__ __launch_bounds__(256) void combine_xp(const float* __restrict__ part,
                                                  float* __restrict__ proj,
                                                  unsigned short* __restrict__ dtlow) {
  int i = blockIdx.x * 256 + threadIdx.x;  // < 2048*128/4
  float4 s = ((const float4*)part)[i];
#pragma unroll
  for (int z = 1; z < 16; ++z) {
    float4 p = ((const float4*)(part + (size_t)z * L_SEQ * 128))[i];
    s.x += p.x; s.y += p.y; s.z += p.z; s.w += p.w;
  }
  ((float4*)proj)[i] = s;
  int c4 = i & 31;  // (col/4)
  if (c4 < 16) {
    int r = i >> 5;
    ushort4 o;
    o.x = f32_bf16(s.x); o.y = f32_bf16(s.y); o.z = f32_bf16(s.z); o.w = f32_bf16(s.w);
    ((ushort4*)dtlow)[r * 16 + c4] = o;
  }
}

// ---------------- causal depthwise conv (k=4) + SiLU (bf16 in/out) ----------------
__global__ __launch_bounds__(256) void conv_silu_kernel(const unsigned short* __restrict__ xzb,
                                                        const float* __restrict__ cw,
                                                        const float* __restrict__ cb,
                                                        unsigned short* __restrict__ xconv_bf) {
  int d = blockIdx.x * 256 + threadIdx.x;  // 0..2047
  int lb = blockIdx.y * 8;
  float w0 = cw[d * 4 + 0], w1 = cw[d * 4 + 1], w2 = cw[d * 4 + 2], w3 = cw[d * 4 + 3];
  float bias = cb[d];
  float xm3 = (lb >= 3) ? bf16_f32(xzb[(size_t)(lb - 3) * 4096 + d]) : 0.f;
  float xm2 = (lb >= 2) ? bf16_f32(xzb[(size_t)(lb - 2) * 4096 + d]) : 0.f;
  float xm1 = (lb >= 1) ? bf16_f32(xzb[(size_t)(lb - 1) * 4096 + d]) : 0.f;
#pragma unroll
  for (int j = 0; j < 8; ++j) {
    int l = lb + j;
    float cur = bf16_f32(xzb[(size_t)l * 4096 + d]);
    float s = bias + w0 * xm3 + w1 * xm2 + w2 * xm1 + w3 * cur;
    s = s / (1.f + __expf(-s));
    xconv_bf[(size_t)l * 2048 + d] = f32_bf16(s);
    xm3 = xm2; xm2 = xm1; xm1 = cur;
  }
}

// ---------------- chunked selective scan (lane owns channel d, 16 states in regs) ----------------
__global__ __launch_bounds__(256) void scan_passA(const float* __restrict__ dt,
                                                  const unsigned short* __restrict__ xc_bf,
                                                  const float* __restrict__ proj,
                                                  const float* __restrict__ A_log,
                                                  float* __restrict__ Pprod,
                                                  float* __restrict__ hend) {
  __shared__ float bc[T_CHUNK][32];
  const int tid = threadIdx.x;
  const int c = blockIdx.y;
  const int t0 = c * T_CHUNK;
  {
    int t = tid >> 3, j = (tid & 7) * 4;
    *(float4*)&bc[t][j] = *(const float4*)&proj[(size_t)(t0 + t) * 128 + 64 + j];
  }
  __syncthreads();
  const int d = blockIdx.x * 256 + tid;
  float A[16];
#pragma unroll
  for (int q = 0; q < 4; ++q) {
    float4 al = ((const float4*)(A_log + (size_t)d * 16))[q];
    A[q * 4 + 0] = -__expf(al.x);
    A[q * 4 + 1] = -__expf(al.y);
    A[q * 4 + 2] = -__expf(al.z);
    A[q * 4 + 3] = -__expf(al.w);
  }
  float h[16], P[16];
#pragma unroll
  for (int n = 0; n < 16; ++n) { h[n] = 0.f; P[n] = 1.f; }

  const int TC = 8;
  float pd[TC];
  unsigned short px[TC];
#pragma unroll
  for (int j = 0; j < TC; ++j) {
    pd[j] = dt[(size_t)(t0 + j) * 2048 + d];
    px[j] = xc_bf[(size_t)(t0 + j) * 2048 + d];
  }
  for (int tb = 0; tb < T_CHUNK; tb += TC) {
    float cd[TC], cx[TC];
#pragma unroll
    for (int j = 0; j < TC; ++j) { cd[j] = pd[j]; cx[j] = bf16_f32(px[j]); }
    if (tb + TC < T_CHUNK) {
#pragma unroll
      for (int j = 0; j < TC; ++j) {
        pd[j] = dt[(size_t)(t0 + tb + TC + j) * 2048 + d];
        px[j] = xc_bf[(size_t)(t0 + tb + TC + j) * 2048 + d];
      }
    }
#pragma unroll
    for (int j = 0; j < TC; ++j) {
      int t = tb + j;
      float dtv = cd[j];
      float dtx = dtv * cx[j];
      float4 B0 = *(const float4*)&bc[t][0];
      float4 B1 = *(const float4*)&bc[t][4];
      float4 B2 = *(const float4*)&bc[t][8];
      float4 B3 = *(const float4*)&bc[t][12];
      float Bv[16] = {B0.x, B0.y, B0.z, B0.w, B1.x, B1.y, B1.z, B1.w,
                      B2.x, B2.y, B2.z, B2.w, B3.x, B3.y, B3.z, B3.w};
#pragma unroll
      for (int n = 0; n < 16; ++n) {
        float da = __expf(dtv * A[n]);
        P[n] *= da;
        h[n] = __builtin_fmaf(da, h[n], dtx * Bv[n]);
      }
    }
  }
  size_t base = ((size_t)c * 2048 + d) * 16;
#pragma unroll
  for (int q = 0; q < 4; ++q) {
    ((float4*)(Pprod + base))[q] = make_float4(P[q * 4], P[q * 4 + 1], P[q * 4 + 2], P[q * 4 + 3]);
    ((float4*)(hend + base))[q] = make_float4(h[q * 4], h[q * 4 + 1], h[q * 4 + 2], h[q * 4 + 3]);
  }
}

__global__ __launch_bounds__(256) void scan_prefix(const float* __restrict__ Pprod,
                                                   const float* __restrict__ hend,
                                                   float* __restrict__ hinit) {
  int i = blockIdx.x * 256 + threadIdx.x;  // 0..32767 = d*16+n
  float h = 0.f;
  const int TC = 8;
  float pP[TC], pH[TC];
#pragma unroll
  for (int j = 0; j < TC; ++j) {
    pP[j] = Pprod[((size_t)j << 15) + i];
    pH[j] = hend[((size_t)j << 15) + i];
  }
  for (int cb = 0; cb < N_CHUNK; cb += TC) {
    float cP[TC], cH[TC];
#pragma unroll
    for (int j = 0; j < TC; ++j) { cP[j] = pP[j]; cH[j] = pH[j]; }
    if (cb + TC < N_CHUNK) {
#pragma unroll
      for (int j = 0; j < TC; ++j) {
        pP[j] = Pprod[((size_t)(cb + TC + j) << 15) + i];
        pH[j] = hend[((size_t)(cb + TC + j) << 15) + i];
      }
    }
#pragma unroll
    for (int j = 0; j < TC; ++j) {
      hinit[((size_t)(cb + j) << 15) + i] = h;
      h = __builtin_fmaf(cP[j], h, cH[j]);
    }
  }
}

__global__ __launch_bounds__(256) void scan_passB(const float* __restrict__ dt,
                                                  const unsigned short* __restrict__ xc_bf,
                                                  const float* __restrict__ proj,
                                                  const unsigned short* __restrict__ xzb,
                                                  const float* __restrict__ A_log,
                                                  const float* __restrict__ Dskip,
                                                  const float* __restrict__ hinit,
                                                  unsigned short* __restrict__ ybf) {
  __shared__ float bc[T_CHUNK][32];
  const int tid = threadIdx.x;
  const int c = blockIdx.y;
  const int t0 = c * T_CHUNK;
  {
    int t = tid >> 3, j = (tid & 7) * 4;
    *(float4*)&bc[t][j] = *(const float4*)&proj[(size_t)(t0 + t) * 128 + 64 + j];
  }
  __syncthreads();
  const int d = blockIdx.x * 256 + tid;
  float A[16];
#pragma unroll
  for (int q = 0; q < 4; ++q) {
    float4 al = ((const float4*)(A_log + (size_t)d * 16))[q];
    A[q * 4 + 0] = -__expf(al.x);
    A[q * 4 + 1] = -__expf(al.y);
    A[q * 4 + 2] = -__expf(al.z);
    A[q * 4 + 3] = -__expf(al.w);
  }
  const float Dv = Dskip[d];
  float h[16];
  {
    size_t base = ((size_t)c * 2048 + d) * 16;
#pragma unroll
    for (int q = 0; q < 4; ++q) {
      float4 hv = ((const float4*)(hinit + base))[q];
      h[q * 4 + 0] = hv.x; h[q * 4 + 1] = hv.y; h[q * 4 + 2] = hv.z; h[q * 4 + 3] = hv.w;
    }
  }
  const int TC = 8;
  float pd[TC];
  unsigned short px[TC], pz[TC];
#pragma unroll
  for (int j = 0; j < TC; ++j) {
    pd[j] = dt[(size_t)(t0 + j) * 2048 + d];
    px[j] = xc_bf[(size_t)(t0 + j) * 2048 + d];
    pz[j] = xzb[(size_t)(t0 + j) * 4096 + 2048 + d];
  }
  for (int tb = 0; tb < T_CHUNK; tb += TC) {
    float cd[TC], cx[TC], cz[TC];
#pragma unroll
    for (int j = 0; j < TC; ++j) {
      cd[j] = pd[j]; cx[j] = bf16_f32(px[j]); cz[j] = bf16_f32(pz[j]);
    }
    if (tb + TC < T_CHUNK) {
#pragma unroll
      for (int j = 0; j < TC; ++j) {
        pd[j] = dt[(size_t)(t0 + tb + TC + j) * 2048 + d];
        px[j] = xc_bf[(size_t)(t0 + tb + TC + j) * 2048 + d];
        pz[j] = xzb[(size_t)(t0 + tb + TC + j) * 4096 + 2048 + d];
      }
    }
#pragma unroll
    for (int j = 0; j < TC; ++j) {
      int t = tb + j;
      float dtv = cd[j];
      float xv = cx[j];
      float dtx = dtv * xv;
      float4 B0 = *(const float4*)&bc[t][0];
      float4 B1 = *(const float4*)&bc[t][4];
      float4 B2 = *(const float4*)&bc[t][8];
      float4 B3 = *(const float4*)&bc[t][12];
      float4 C0 = *(const float4*)&bc[t][16];
      float4 C1 = *(const float4*)&bc[t][20];
      float4 C2 = *(const float4*)&bc[t][24];
      float4 C3 = *(const float4*)&bc[t][28];
      float Bv[16] = {B0.x, B0.y, B0.z, B0.w, B1.x, B1.y, B1.z, B1.w,
                      B2.x, B2.y, B2.z, B2.w, B3.x, B3.y, B3.z, B3.w};
      float Cv[16] = {C0.x, C0.y, C0.z, C0.w, C1.x, C1.y, C1.z, C1.w,
                      C2.x, C2.y, C2.z, C2.w, C3.x, C3.y, C3.z, C3.w};
      float y = 0.f;
#pragma unroll
      for (int n = 0; n < 16; ++n) {
        float da = __expf(dtv * A[n]);
        h[n] = __builtin_fmaf(da, h[n], dtx * Bv[n]);
        y = __builtin_fmaf(h[n], Cv[n], y);
      }
      float zv = cz[j];
      float yv = y + xv * Dv;
      yv *= zv / (1.f + __expf(-zv));
      ybf[(size_t)(t0 + t) * 2048 + d] = f32_bf16(yv);
    }
  }
}

// ---------------- launcher ----------------
extern "C" void kernel_launch(void* const* d_in, const int* in_sizes, int n_in,
                              void* d_out, int out_size, void* d_ws, size_t ws_size,
                              hipStream_t stream) {
  const float* x      = (const float*)d_in[0];
  const float* ln_w   = (const float*)d_in[1];
  const float* ln_b   = (const float*)d_in[2];
  const float* W_in   = (const float*)d_in[3];
  const float* conv_w = (const float*)d_in[4];
  const float* conv_b = (const float*)d_in[5];
  const float* W_xproj= (const float*)d_in[6];
  const float* W_dt   = (const float*)d_in[7];
  const float* b_dt   = (const float*)d_in[8];
  const float* A_log  = (const float*)d_in[9];
  const float* Dskip  = (const float*)d_in[10];
  const float* W_out  = (const float*)d_in[11];
  float* out = (float*)d_out;

  char* ws = (char*)d_ws;
  size_t off = 0;
  auto alloc = [&](size_t bytes) {
    void* p = ws + off;
    off = (off + bytes + 255) & ~(size_t)255;
    return p;
  };
  unsigned short* xn_bf      = (unsigned short*)alloc((size_t)L_SEQ * D_MODEL * 2);
  unsigned short* W_in_bf    = (unsigned short*)alloc((size_t)2 * D_INNER * D_MODEL * 2);
  unsigned short* W_xprojp   = (unsigned short*)alloc((size_t)128 * D_INNER * 2);
  unsigned short* W_dt_bf    = (unsigned short*)alloc((size_t)D_INNER * DT_RANK * 2);
  unsigned short* W_out_bf   = (unsigned short*)alloc((size_t)D_MODEL * D_INNER * 2);
  unsigned short* xz_bf      = (unsigned short*)alloc((size_t)L_SEQ * 2 * D_INNER * 2);
  unsigned short* xconv_bf   = (unsigned short*)alloc((size_t)L_SEQ * D_INNER * 2);
  float*          proj       = (float*)alloc((size_t)L_SEQ * 128 * 4);
  unsigned short* dtlow_bf   = (unsigned short*)alloc((size_t)L_SEQ * DT_RANK * 2);
  float*          dtf        = (float*)alloc((size_t)L_SEQ * D_INNER * 4);
  unsigned short* y_bf       = (unsigned short*)alloc((size_t)L_SEQ * D_INNER * 2);
  float*          Pprod      = (float*)alloc((size_t)N_CHUNK * D_INNER * D_STATE * 4);
  float*          hend       = (float*)alloc((size_t)N_CHUNK * D_INNER * D_STATE * 4);
  float*          hinit      = (float*)alloc((size_t)N_CHUNK * D_INNER * D_STATE * 4);
  float*          part_xp    = (float*)alloc((size_t)16 * L_SEQ * 128 * 4);     // 16 MB
  float*          part_out   = (float*)alloc((size_t)4 * L_SEQ * D_MODEL * 4);  // 32 MB

  // weight converts
  cvt_f32_bf16_4<<<(2 * D_INNER * D_MODEL / 4 + 255) / 256, 256, 0, stream>>>(W_in, W_in_bf, 2 * D_INNER * D_MODEL / 4);
  cvt_f32_bf16_4<<<(D_MODEL * D_INNER / 4 + 255) / 256, 256, 0, stream>>>(W_out, W_out_bf, D_MODEL * D_INNER / 4);
  cvt_f32_bf16_4<<<(D_INNER * DT_RANK / 4 + 255) / 256, 256, 0, stream>>>(W_dt, W_dt_bf, D_INNER * DT_RANK / 4);
  cvt_pad_xproj<<<128 * 2048 / 256, 256, 0, stream>>>(W_xproj, W_xprojp);

  // layernorm -> xn bf16
  ln_kernel<<<L_SEQ, 256, 0, stream>>>(x, ln_w, ln_b, xn_bf);

  // in_proj: xz = xn @ W_in^T   (M=2048, N=4096, K=1024) -> bf16
  gemm_bt<0, false, true><<<dim3(32, 16, 1), 256, 0, stream>>>(xn_bf, W_in_bf, xz_bf, L_SEQ, 4096, 1024, 1024, nullptr);

  // depthwise conv + SiLU on xc = xz[:, :2048] (bf16 -> bf16)
  conv_silu_kernel<<<dim3(D_INNER / 256, L_SEQ / 8), 256, 0, stream>>>(xz_bf, conv_w, conv_b, xconv_bf);

  // x_proj: proj = xconv @ W_xprojp^T  (M=2048, N=128(pad), K=2048), split-K 16
  gemm_bt<0, true, false><<<dim3(1, 16, 16), 256, 0, stream>>>(xconv_bf, W_xprojp, part_xp, L_SEQ, 128, 2048, 128, nullptr);
  combine_xp<<<(L_SEQ * 128 / 4) / 256, 256, 0, stream>>>(part_xp, proj, dtlow_bf);

  // dt = softplus(dtlow @ W_dt^T + b_dt)  (M=2048, N=2048, K=64) -> f32
  gemm_bt<1, false, false><<<dim3(16, 16, 1), 256, 0, stream>>>(dtlow_bf, W_dt_bf, dtf, L_SEQ, 2048, 64, 64, b_dt);

  // chunked selective scan (transposed: lane owns a channel, 16 states in registers)
  scan_passA<<<dim3(D_INNER / 256, N_CHUNK), 256, 0, stream>>>(dtf, xconv_bf, proj, A_log, Pprod, hend);
  scan_prefix<<<128, 256, 0, stream>>>(Pprod, hend, hinit);
  scan_passB<<<dim3(D_INNER / 256, N_CHUNK), 256, 0, stream>>>(dtf, xconv_bf, proj, xz_bf, A_log, Dskip, hinit, y_bf);

  // out_proj (M=2048, N=1024, K=2048), split-K 4; combine adds residual
  gemm_bt<0, true, false><<<dim3(8, 16, 4), 256, 0, stream>>>(y_bf, W_out_bf, part_out, L_SEQ, 1024, 2048, 512, nullptr);
  combine_out<<<(L_SEQ * D_MODEL / 4) / 256, 256, 0, stream>>>(part_out, out, L_SEQ * D_MODEL / 4, x);
}

// Round 6
// 171.838 us; speedup vs baseline: 4.3785x; 1.0416x over previous
//
#include <hip/hip_runtime.h>

typedef __bf16 bf16x8 __attribute__((ext_vector_type(8)));
typedef float floatx4 __attribute__((ext_vector_type(4)));
typedef unsigned short ushort8 __attribute__((ext_vector_type(8)));

#define L_SEQ 2048
#define D_MODEL 1024
#define D_INNER 2048
#define D_STATE 16
#define DT_RANK 64

#define N_CHUNK 64
#define T_CHUNK 32  // L_SEQ / N_CHUNK

__device__ __forceinline__ unsigned short f32_bf16(float f) {
  unsigned int u = __builtin_bit_cast(unsigned int, f);
  u += 0x7fffu + ((u >> 16) & 1u);
  return (unsigned short)(u >> 16);
}
__device__ __forceinline__ float bf16_f32(unsigned short u) {
  return __builtin_bit_cast(float, (unsigned int)u << 16);
}

// async global->LDS, 16B per lane; lds base must be wave-uniform (m104)
__device__ __forceinline__ void stage16(const unsigned short* g, unsigned short* l) {
  __builtin_amdgcn_global_load_lds((const __attribute__((address_space(1))) unsigned int*)g,
                                   (__attribute__((address_space(3))) unsigned int*)l, 16, 0, 0);
}

// ---------------- converts ----------------
__global__ __launch_bounds__(256) void cvt_f32_bf16_4(const float* __restrict__ in,
                                                      unsigned short* __restrict__ out, int n4) {
  int i = blockIdx.x * 256 + threadIdx.x;
  if (i < n4) {
    float4 v = ((const float4*)in)[i];
    ushort4 o;
    o.x = f32_bf16(v.x); o.y = f32_bf16(v.y); o.z = f32_bf16(v.z); o.w = f32_bf16(v.w);
    ((ushort4*)out)[i] = o;
  }
}

// W_xproj (96 x 2048) -> bf16 padded to (128 x 2048)
__global__ __launch_bounds__(256) void cvt_pad_xproj(const float* __restrict__ in,
                                                     unsigned short* __restrict__ out) {
  int i = blockIdx.x * 256 + threadIdx.x;  // < 128*2048
  int r = i >> 11, c = i & 2047;
  out[i] = (r < 96) ? f32_bf16(in[r * 2048 + c]) : (unsigned short)0;
}

// ---------------- layernorm -> bf16 ----------------
__global__ __launch_bounds__(256) void ln_kernel(const float* __restrict__ x,
                                                 const float* __restrict__ w,
                                                 const float* __restrict__ b,
                                                 unsigned short* __restrict__ xn) {
  int row = blockIdx.x, tid = threadIdx.x;
  const float4 v = ((const float4*)(x + (size_t)row * D_MODEL))[tid];
  float s = v.x + v.y + v.z + v.w;
  float q = v.x * v.x + v.y * v.y + v.z * v.z + v.w * v.w;
#pragma unroll
  for (int o = 1; o < 64; o <<= 1) {
    s += __shfl_xor(s, o);
    q += __shfl_xor(q, o);
  }
  __shared__ float red[8];
  int wv = tid >> 6;
  if ((tid & 63) == 0) { red[wv] = s; red[4 + wv] = q; }
  __syncthreads();
  s = red[0] + red[1] + red[2] + red[3];
  q = red[4] + red[5] + red[6] + red[7];
  float mu = s * (1.f / 1024.f);
  float var = q * (1.f / 1024.f) - mu * mu;
  float rs = rsqrtf(var + 1e-5f);
  float4 wv4 = ((const float4*)w)[tid];
  float4 bv4 = ((const float4*)b)[tid];
  ushort4 o;
  o.x = f32_bf16((v.x - mu) * rs * wv4.x + bv4.x);
  o.y = f32_bf16((v.y - mu) * rs * wv4.y + bv4.y);
  o.z = f32_bf16((v.z - mu) * rs * wv4.z + bv4.z);
  o.w = f32_bf16((v.w - mu) * rs * wv4.w + bv4.w);
  ((ushort4*)(xn + (size_t)row * D_MODEL))[tid] = o;
}

// ---------------- GEMM: C[M][N] = A[M][K] * B[N][K]^T (bf16 in) ----------------
// global_load_lds staging (m97 structure), linear LDS [rows][32]. BM=128, BN=64 or 128.
// EPI: 0 = plain, 1 = softplus(v + bias[col])
// PARTIAL: write f32 partial tile at C + kz*M*N (no epilogue). OBF: write bf16.
template <int BN, int EPI, bool PARTIAL, bool OBF>
__global__ __launch_bounds__(256) void gemm_bt(const unsigned short* __restrict__ A,
                                               const unsigned short* __restrict__ B,
                                               void* __restrict__ Cout, int M, int N, int K,
                                               int klen, const float* __restrict__ extra) {
  constexpr int NN = BN / 32;  // per-wave 16-col accumulator count
  __shared__ unsigned short As[128 * 32];
  __shared__ unsigned short Bs[BN * 32];
  const int tid = threadIdx.x;
  const int lane = tid & 63, wave = tid >> 6;
  const int wr = wave >> 1, wc = wave & 1;
  const int rl = lane & 15, kg = lane >> 4;
  // XCD-aware swizzle on flattened (bx,by); all our grids have nwg % 8 == 0
  const int gx = gridDim.x;
  const int nwg = gx * gridDim.y;
  const int bid = blockIdx.y * gx + blockIdx.x;
  const int swz = (bid & 7) * (nwg >> 3) + (bid >> 3);
  const int bx = swz % gx, by = swz / gx, kz = blockIdx.z;
  const unsigned short* Ab = A + (size_t)by * 128 * K;
  const unsigned short* Bb = B + (size_t)bx * BN * K;
  const int srow = wave * 16 + (lane >> 2);
  const int scol = (lane & 3) * 8;
  unsigned short* la0 = As + wave * 512;
  unsigned short* la1 = As + 2048 + wave * 512;
  unsigned short* lb0 = Bs + wave * 512;
  const int kbeg = kz * klen, kend = kbeg + klen;
  floatx4 acc[4][NN] = {};
  for (int k0 = kbeg; k0 < kend; k0 += 32) {
    const unsigned short* ga = Ab + (size_t)srow * K + k0 + scol;
    const unsigned short* gb = Bb + (size_t)srow * K + k0 + scol;
    stage16(ga, la0);
    stage16(ga + (size_t)64 * K, la1);
    stage16(gb, lb0);
    if constexpr (BN == 128) stage16(gb + (size_t)64 * K, Bs + 2048 + wave * 512);
    __syncthreads();  // drains vmcnt -> LDS tiles ready
    bf16x8 af[4], bfr[NN];
#pragma unroll
    for (int m = 0; m < 4; ++m)
      af[m] = *(const bf16x8*)&As[(wr * 64 + m * 16 + rl) * 32 + kg * 8];
#pragma unroll
    for (int n = 0; n < NN; ++n)
      bfr[n] = *(const bf16x8*)&Bs[(wc * (BN / 2) + n * 16 + rl) * 32 + kg * 8];
#pragma unroll
    for (int m = 0; m < 4; ++m)
#pragma unroll
      for (int n = 0; n < NN; ++n)
        acc[m][n] = __builtin_amdgcn_mfma_f32_16x16x32_bf16(af[m], bfr[n], acc[m][n], 0, 0, 0);
    __syncthreads();  // before overwriting tiles
  }
  float* Cf = PARTIAL ? (float*)Cout + (size_t)kz * M * N : (float*)Cout;
  unsigned short* Cb = (unsigned short*)Cout;
#pragma unroll
  for (int m = 0; m < 4; ++m) {
#pragma unroll
    for (int n = 0; n < NN; ++n) {
      int col = bx * BN + wc * (BN / 2) + n * 16 + rl;
#pragma unroll
      for (int j = 0; j < 4; ++j) {
        int rowg = by * 128 + wr * 64 + m * 16 + kg * 4 + j;
        float v = acc[m][n][j];
        if (!PARTIAL && EPI == 1) {
          v += extra[col];
          v = (v > 20.f) ? v : log1pf(__expf(v));
        }
        if (OBF)
          Cb[(size_t)rowg * N + col] = f32_bf16(v);
        else
          Cf[(size_t)rowg * N + col] = v;
      }
    }
  }
}

// ---------------- split-K combines ----------------
// NS partials; EPI: 0 = plain, 2 = add extra (residual) elementwise
template <int NS, int EPI>
__global__ __launch_bounds__(256) void combine_k(const float* __restrict__ part,
                                                 float* __restrict__ out, int MN4,
                                                 const float* __restrict__ extra) {
  int i = blockIdx.x * 256 + threadIdx.x;
  if (i >= MN4) return;
  float4 s = ((const float4*)part)[i];
#pragma unroll
  for (int z = 1; z < NS; ++z) {
    float4 p = ((const float4*)(part + (size_t)z * MN4 * 4))[i];
    s.x += p.x; s.y += p.y; s.z += p.z; s.w += p.w;
  }
  if (EPI == 2) {
    float4 e = ((const float4*)extra)[i];
    s.x += e.x; s.y += e.y; s.z += e.z; s.w += e.w;
  }
  ((float4*)out)[i] = s;
}

// x-proj: proj = sum_z part[z]; also emit dtlow bf16 for cols [0,64)
__global__ __launch_bounds__(256) void combine_xp(const float* __restrict__ part,
                                                  float* __restrict__ proj,
                                                  unsigned short* __restrict__ dtlow) {
  int i = blockIdx.x * 256 + threadIdx.x;  // < 2048*128/4
  float4 s = ((const float4*)part)[i];
#pragma unroll
  for (int z = 1; z < 16; ++z) {
    float4 p = ((const float4*)(part + (size_t)z * L_SEQ * 128))[i];
    s.x += p.x; s.y += p.y; s.z += p.z; s.w += p.w;
  }
  ((float4*)proj)[i] = s;
  int c4 = i & 31;  // (col/4)
  if (c4 < 16) {
    int r = i >> 5;
    ushort4 o;
    o.x = f32_bf16(s.x); o.y = f32_bf16(s.y); o.z = f32_bf16(s.z); o.w = f32_bf16(s.w);
    ((ushort4*)dtlow)[r * 16 + c4] = o;
  }
}

// ---------------- causal depthwise conv (k=4) + SiLU (bf16 in/out) ----------------
__global__ __launch_bounds__(256) void conv_silu_kernel(const unsigned short* __restrict__ xzb,
                                                        const float* __restrict__ cw,
                                                        const float* __restrict__ cb,
                                                        unsigned short* __restrict__ xconv_bf) {
  int d = blockIdx.x * 256 + threadIdx.x;  // 0..2047
  int lb = blockIdx.y * 8;
  float w0 = cw[d * 4 + 0], w1 = cw[d * 4 + 1], w2 = cw[d * 4 + 2], w3 = cw[d * 4 + 3];
  float bias = cb[d];
  float xm3 = (lb >= 3) ? bf16_f32(xzb[(size_t)(lb - 3) * 4096 + d]) : 0.f;
  float xm2 = (lb >= 2) ? bf16_f32(xzb[(size_t)(lb - 2) * 4096 + d]) : 0.f;
  float xm1 = (lb >= 1) ? bf16_f32(xzb[(size_t)(lb - 1) * 4096 + d]) : 0.f;
#pragma unroll
  for (int j = 0; j < 8; ++j) {
    int l = lb + j;
    float cur = bf16_f32(xzb[(size_t)l * 4096 + d]);
    float s = bias + w0 * xm3 + w1 * xm2 + w2 * xm1 + w3 * cur;
    s = s / (1.f + __expf(-s));
    xconv_bf[(size_t)l * 2048 + d] = f32_bf16(s);
    xm3 = xm2; xm2 = xm1; xm1 = cur;
  }
}

// ---------------- chunked selective scan (lane owns channel d, 16 states in regs) ----------------
__global__ __launch_bounds__(256) void scan_passA(const float* __restrict__ dt,
                                                  const unsigned short* __restrict__ xc_bf,
                                                  const float* __restrict__ proj,
                                                  const float* __restrict__ A_log,
                                                  float* __restrict__ Pprod,
                                                  float* __restrict__ hend) {
  __shared__ float bc[T_CHUNK][32];
  const int tid = threadIdx.x;
  const int c = blockIdx.y;
  const int t0 = c * T_CHUNK;
  {
    int t = tid >> 3, j = (tid & 7) * 4;
    *(float4*)&bc[t][j] = *(const float4*)&proj[(size_t)(t0 + t) * 128 + 64 + j];
  }
  __syncthreads();
  const int d = blockIdx.x * 256 + tid;
  float A[16];
#pragma unroll
  for (int q = 0; q < 4; ++q) {
    float4 al = ((const float4*)(A_log + (size_t)d * 16))[q];
    A[q * 4 + 0] = -__expf(al.x);
    A[q * 4 + 1] = -__expf(al.y);
    A[q * 4 + 2] = -__expf(al.z);
    A[q * 4 + 3] = -__expf(al.w);
  }
  float h[16], P[16];
#pragma unroll
  for (int n = 0; n < 16; ++n) { h[n] = 0.f; P[n] = 1.f; }

  const int TC = 8;
  float pd[TC];
  unsigned short px[TC];
#pragma unroll
  for (int j = 0; j < TC; ++j) {
    pd[j] = dt[(size_t)(t0 + j) * 2048 + d];
    px[j] = xc_bf[(size_t)(t0 + j) * 2048 + d];
  }
  for (int tb = 0; tb < T_CHUNK; tb += TC) {
    float cd[TC], cx[TC];
#pragma unroll
    for (int j = 0; j < TC; ++j) { cd[j] = pd[j]; cx[j] = bf16_f32(px[j]); }
    if (tb + TC < T_CHUNK) {
#pragma unroll
      for (int j = 0; j < TC; ++j) {
        pd[j] = dt[(size_t)(t0 + tb + TC + j) * 2048 + d];
        px[j] = xc_bf[(size_t)(t0 + tb + TC + j) * 2048 + d];
      }
    }
#pragma unroll
    for (int j = 0; j < TC; ++j) {
      int t = tb + j;
      float dtv = cd[j];
      float dtx = dtv * cx[j];
      float4 B0 = *(const float4*)&bc[t][0];
      float4 B1 = *(const float4*)&bc[t][4];
      float4 B2 = *(const float4*)&bc[t][8];
      float4 B3 = *(const float4*)&bc[t][12];
      float Bv[16] = {B0.x, B0.y, B0.z, B0.w, B1.x, B1.y, B1.z, B1.w,
                      B2.x, B2.y, B2.z, B2.w, B3.x, B3.y, B3.z, B3.w};
#pragma unroll
      for (int n = 0; n < 16; ++n) {
        float da = __expf(dtv * A[n]);
        P[n] *= da;
        h[n] = __builtin_fmaf(da, h[n], dtx * Bv[n]);
      }
    }
  }
  size_t base = ((size_t)c * 2048 + d) * 16;
#pragma unroll
  for (int q = 0; q < 4; ++q) {
    ((float4*)(Pprod + base))[q] = make_float4(P[q * 4], P[q * 4 + 1], P[q * 4 + 2], P[q * 4 + 3]);
    ((float4*)(hend + base))[q] = make_float4(h[q * 4], h[q * 4 + 1], h[q * 4 + 2], h[q * 4 + 3]);
  }
}

__global__ __launch_bounds__(256) void scan_prefix(const float* __restrict__ Pprod,
                                                   const float* __restrict__ hend,
                                                   float* __restrict__ hinit) {
  int i = blockIdx.x * 256 + threadIdx.x;  // 0..32767 = d*16+n
  float h = 0.f;
  const int TC = 8;
  float pP[TC], pH[TC];
#pragma unroll
  for (int j = 0; j < TC; ++j) {
    pP[j] = Pprod[((size_t)j << 15) + i];
    pH[j] = hend[((size_t)j << 15) + i];
  }
  for (int cb = 0; cb < N_CHUNK; cb += TC) {
    float cP[TC], cH[TC];
#pragma unroll
    for (int j = 0; j < TC; ++j) { cP[j] = pP[j]; cH[j] = pH[j]; }
    if (cb + TC < N_CHUNK) {
#pragma unroll
      for (int j = 0; j < TC; ++j) {
        pP[j] = Pprod[((size_t)(cb + TC + j) << 15) + i];
        pH[j] = hend[((size_t)(cb + TC + j) << 15) + i];
      }
    }
#pragma unroll
    for (int j = 0; j < TC; ++j) {
      hinit[((size_t)(cb + j) << 15) + i] = h;
      h = __builtin_fmaf(cP[j], h, cH[j]);
    }
  }
}

__global__ __launch_bounds__(256) void scan_passB(const float* __restrict__ dt,
                                                  const unsigned short* __restrict__ xc_bf,
                                                  const float* __restrict__ proj,
                                                  const unsigned short* __restrict__ xzb,
                                                  const float* __restrict__ A_log,
                                                  const float* __restrict__ Dskip,
                                                  const float* __restrict__ hinit,
                                                  unsigned short* __restrict__ ybf) {
  __shared__ float bc[T_CHUNK][32];
  const int tid = threadIdx.x;
  const int c = blockIdx.y;
  const int t0 = c * T_CHUNK;
  {
    int t = tid >> 3, j = (tid & 7) * 4;
    *(float4*)&bc[t][j] = *(const float4*)&proj[(size_t)(t0 + t) * 128 + 64 + j];
  }
  __syncthreads();
  const int d = blockIdx.x * 256 + tid;
  float A[16];
#pragma unroll
  for (int q = 0; q < 4; ++q) {
    float4 al = ((const float4*)(A_log + (size_t)d * 16))[q];
    A[q * 4 + 0] = -__expf(al.x);
    A[q * 4 + 1] = -__expf(al.y);
    A[q * 4 + 2] = -__expf(al.z);
    A[q * 4 + 3] = -__expf(al.w);
  }
  const float Dv = Dskip[d];
  float h[16];
  {
    size_t base = ((size_t)c * 2048 + d) * 16;
#pragma unroll
    for (int q = 0; q < 4; ++q) {
      float4 hv = ((const float4*)(hinit + base))[q];
      h[q * 4 + 0] = hv.x; h[q * 4 + 1] = hv.y; h[q * 4 + 2] = hv.z; h[q * 4 + 3] = hv.w;
    }
  }
  const int TC = 8;
  float pd[TC];
  unsigned short px[TC], pz[TC];
#pragma unroll
  for (int j = 0; j < TC; ++j) {
    pd[j] = dt[(size_t)(t0 + j) * 2048 + d];
    px[j] = xc_bf[(size_t)(t0 + j) * 2048 + d];
    pz[j] = xzb[(size_t)(t0 + j) * 4096 + 2048 + d];
  }
  for (int tb = 0; tb < T_CHUNK; tb += TC) {
    float cd[TC], cx[TC], cz[TC];
#pragma unroll
    for (int j = 0; j < TC; ++j) {
      cd[j] = pd[j]; cx[j] = bf16_f32(px[j]); cz[j] = bf16_f32(pz[j]);
    }
    if (tb + TC < T_CHUNK) {
#pragma unroll
      for (int j = 0; j < TC; ++j) {
        pd[j] = dt[(size_t)(t0 + tb + TC + j) * 2048 + d];
        px[j] = xc_bf[(size_t)(t0 + tb + TC + j) * 2048 + d];
        pz[j] = xzb[(size_t)(t0 + tb + TC + j) * 4096 + 2048 + d];
      }
    }
#pragma unroll
    for (int j = 0; j < TC; ++j) {
      int t = tb + j;
      float dtv = cd[j];
      float xv = cx[j];
      float dtx = dtv * xv;
      float4 B0 = *(const float4*)&bc[t][0];
      float4 B1 = *(const float4*)&bc[t][4];
      float4 B2 = *(const float4*)&bc[t][8];
      float4 B3 = *(const float4*)&bc[t][12];
      float4 C0 = *(const float4*)&bc[t][16];
      float4 C1 = *(const float4*)&bc[t][20];
      float4 C2 = *(const float4*)&bc[t][24];
      float4 C3 = *(const float4*)&bc[t][28];
      float Bv[16] = {B0.x, B0.y, B0.z, B0.w, B1.x, B1.y, B1.z, B1.w,
                      B2.x, B2.y, B2.z, B2.w, B3.x, B3.y, B3.z, B3.w};
      float Cv[16] = {C0.x, C0.y, C0.z, C0.w, C1.x, C1.y, C1.z, C1.w,
                      C2.x, C2.y, C2.z, C2.w, C3.x, C3.y, C3.z, C3.w};
      float y = 0.f;
#pragma unroll
      for (int n = 0; n < 16; ++n) {
        float da = __expf(dtv * A[n]);
        h[n] = __builtin_fmaf(da, h[n], dtx * Bv[n]);
        y = __builtin_fmaf(h[n], Cv[n], y);
      }
      float zv = cz[j];
      float yv = y + xv * Dv;
      yv *= zv / (1.f + __expf(-zv));
      ybf[(size_t)(t0 + t) * 2048 + d] = f32_bf16(yv);
    }
  }
}

// ---------------- launcher ----------------
extern "C" void kernel_launch(void* const* d_in, const int* in_sizes, int n_in,
                              void* d_out, int out_size, void* d_ws, size_t ws_size,
                              hipStream_t stream) {
  const float* x      = (const float*)d_in[0];
  const float* ln_w   = (const float*)d_in[1];
  const float* ln_b   = (const float*)d_in[2];
  const float* W_in   = (const float*)d_in[3];
  const float* conv_w = (const float*)d_in[4];
  const float* conv_b = (const float*)d_in[5];
  const float* W_xproj= (const float*)d_in[6];
  const float* W_dt   = (const float*)d_in[7];
  const float* b_dt   = (const float*)d_in[8];
  const float* A_log  = (const float*)d_in[9];
  const float* Dskip  = (const float*)d_in[10];
  const float* W_out  = (const float*)d_in[11];
  float* out = (float*)d_out;

  char* ws = (char*)d_ws;
  size_t off = 0;
  auto alloc = [&](size_t bytes) {
    void* p = ws + off;
    off = (off + bytes + 255) & ~(size_t)255;
    return p;
  };
  unsigned short* xn_bf      = (unsigned short*)alloc((size_t)L_SEQ * D_MODEL * 2);
  unsigned short* W_in_bf    = (unsigned short*)alloc((size_t)2 * D_INNER * D_MODEL * 2);
  unsigned short* W_xprojp   = (unsigned short*)alloc((size_t)128 * D_INNER * 2);
  unsigned short* W_dt_bf    = (unsigned short*)alloc((size_t)D_INNER * DT_RANK * 2);
  unsigned short* W_out_bf   = (unsigned short*)alloc((size_t)D_MODEL * D_INNER * 2);
  unsigned short* xz_bf      = (unsigned short*)alloc((size_t)L_SEQ * 2 * D_INNER * 2);
  unsigned short* xconv_bf   = (unsigned short*)alloc((size_t)L_SEQ * D_INNER * 2);
  float*          proj       = (float*)alloc((size_t)L_SEQ * 128 * 4);
  unsigned short* dtlow_bf   = (unsigned short*)alloc((size_t)L_SEQ * DT_RANK * 2);
  float*          dtf        = (float*)alloc((size_t)L_SEQ * D_INNER * 4);
  unsigned short* y_bf       = (unsigned short*)alloc((size_t)L_SEQ * D_INNER * 2);
  float*          Pprod      = (float*)alloc((size_t)N_CHUNK * D_INNER * D_STATE * 4);
  float*          hend       = (float*)alloc((size_t)N_CHUNK * D_INNER * D_STATE * 4);
  float*          hinit      = (float*)alloc((size_t)N_CHUNK * D_INNER * D_STATE * 4);
  float*          part_xp    = (float*)alloc((size_t)16 * L_SEQ * 128 * 4);     // 16 MB
  float*          part_out   = (float*)alloc((size_t)2 * L_SEQ * D_MODEL * 4);  // 16 MB

  // weight converts
  cvt_f32_bf16_4<<<(2 * D_INNER * D_MODEL / 4 + 255) / 256, 256, 0, stream>>>(W_in, W_in_bf, 2 * D_INNER * D_MODEL / 4);
  cvt_f32_bf16_4<<<(D_MODEL * D_INNER / 4 + 255) / 256, 256, 0, stream>>>(W_out, W_out_bf, D_MODEL * D_INNER / 4);
  cvt_f32_bf16_4<<<(D_INNER * DT_RANK / 4 + 255) / 256, 256, 0, stream>>>(W_dt, W_dt_bf, D_INNER * DT_RANK / 4);
  cvt_pad_xproj<<<128 * 2048 / 256, 256, 0, stream>>>(W_xproj, W_xprojp);

  // layernorm -> xn bf16
  ln_kernel<<<L_SEQ, 256, 0, stream>>>(x, ln_w, ln_b, xn_bf);

  // in_proj: xz = xn @ W_in^T  (M=2048, N=4096, K=1024) -> bf16; grid 1024 blocks (4/CU)
  gemm_bt<64, 0, false, true><<<dim3(64, 16, 1), 256, 0, stream>>>(xn_bf, W_in_bf, xz_bf, L_SEQ, 4096, 1024, 1024, nullptr);

  // depthwise conv + SiLU on xc = xz[:, :2048] (bf16 -> bf16)
  conv_silu_kernel<<<dim3(D_INNER / 256, L_SEQ / 8), 256, 0, stream>>>(xz_bf, conv_w, conv_b, xconv_bf);

  // x_proj: proj = xconv @ W_xprojp^T  (M=2048, N=128(pad), K=2048), split-K 16; 512 blocks
  gemm_bt<64, 0, true, false><<<dim3(2, 16, 16), 256, 0, stream>>>(xconv_bf, W_xprojp, part_xp, L_SEQ, 128, 2048, 128, nullptr);
  combine_xp<<<(L_SEQ * 128 / 4) / 256, 256, 0, stream>>>(part_xp, proj, dtlow_bf);

  // dt = softplus(dtlow @ W_dt^T + b_dt)  (M=2048, N=2048, K=64) -> f32; 512 blocks
  gemm_bt<64, 1, false, false><<<dim3(32, 16, 1), 256, 0, stream>>>(dtlow_bf, W_dt_bf, dtf, L_SEQ, 2048, 64, 64, b_dt);

  // chunked selective scan (transposed: lane owns a channel, 16 states in registers)
  scan_passA<<<dim3(D_INNER / 256, N_CHUNK), 256, 0, stream>>>(dtf, xconv_bf, proj, A_log, Pprod, hend);
  scan_prefix<<<128, 256, 0, stream>>>(Pprod, hend, hinit);
  scan_passB<<<dim3(D_INNER / 256, N_CHUNK), 256, 0, stream>>>(dtf, xconv_bf, proj, xz_bf, A_log, Dskip, hinit, y_bf);

  // out_proj (M=2048, N=1024, K=2048), split-K 2; 512 blocks; combine adds residual
  gemm_bt<64, 0, true, false><<<dim3(16, 16, 2), 256, 0, stream>>>(y_bf, W_out_bf, part_out, L_SEQ, 1024, 2048, 1024, nullptr);
  combine_k<2, 2><<<(L_SEQ * D_MODEL / 4) / 256, 256, 0, stream>>>(part_out, out, L_SEQ * D_MODEL / 4, x);
}

// Round 7
// 165.525 us; speedup vs baseline: 4.5455x; 1.0381x over previous
//
#include <hip/hip_runtime.h>

typedef __bf16 bf16x8 __attribute__((ext_vector_type(8)));
typedef float floatx4 __attribute__((ext_vector_type(4)));
typedef unsigned short ushort8 __attribute__((ext_vector_type(8)));

#define L_SEQ 2048
#define D_MODEL 1024
#define D_INNER 2048
#define D_STATE 16
#define DT_RANK 64

#define N_CHUNK 64
#define T_CHUNK 32  // L_SEQ / N_CHUNK

__device__ __forceinline__ unsigned short f32_bf16(float f) {
  unsigned int u = __builtin_bit_cast(unsigned int, f);
  u += 0x7fffu + ((u >> 16) & 1u);
  return (unsigned short)(u >> 16);
}
__device__ __forceinline__ float bf16_f32(unsigned short u) {
  return __builtin_bit_cast(float, (unsigned int)u << 16);
}

// async global->LDS, 16B per lane; lds base must be wave-uniform (m104)
__device__ __forceinline__ void stage16(const unsigned short* g, unsigned short* l) {
  __builtin_amdgcn_global_load_lds((const __attribute__((address_space(1))) unsigned int*)g,
                                   (__attribute__((address_space(3))) unsigned int*)l, 16, 0, 0);
}

// ---------------- converts (fused: W_in, W_out, W_dt) ----------------
#define NI4 1048576  // 2*2048*1024/4
#define NO4 524288   // 1024*2048/4
#define ND4 32768    // 2048*64/4
__global__ __launch_bounds__(256) void cvt_weights(const float* __restrict__ Wi,
                                                   const float* __restrict__ Wo,
                                                   const float* __restrict__ Wd,
                                                   unsigned short* __restrict__ oi,
                                                   unsigned short* __restrict__ oo,
                                                   unsigned short* __restrict__ od) {
  int i = blockIdx.x * 256 + threadIdx.x;
  const float* src;
  unsigned short* dst;
  int j = i;
  if (i < NI4) { src = Wi; dst = oi; }
  else if (i < NI4 + NO4) { src = Wo; dst = oo; j = i - NI4; }
  else if (i < NI4 + NO4 + ND4) { src = Wd; dst = od; j = i - NI4 - NO4; }
  else return;
  float4 v = ((const float4*)src)[j];
  ushort4 o;
  o.x = f32_bf16(v.x); o.y = f32_bf16(v.y); o.z = f32_bf16(v.z); o.w = f32_bf16(v.w);
  ((ushort4*)dst)[j] = o;
}

// W_xproj (96 x 2048) -> bf16 padded to (128 x 2048)
__global__ __launch_bounds__(256) void cvt_pad_xproj(const float* __restrict__ in,
                                                     unsigned short* __restrict__ out) {
  int i = blockIdx.x * 256 + threadIdx.x;  // < 128*2048
  int r = i >> 11, c = i & 2047;
  out[i] = (r < 96) ? f32_bf16(in[r * 2048 + c]) : (unsigned short)0;
}

// ---------------- layernorm -> bf16 ----------------
__global__ __launch_bounds__(256) void ln_kernel(const float* __restrict__ x,
                                                 const float* __restrict__ w,
                                                 const float* __restrict__ b,
                                                 unsigned short* __restrict__ xn) {
  int row = blockIdx.x, tid = threadIdx.x;
  const float4 v = ((const float4*)(x + (size_t)row * D_MODEL))[tid];
  float s = v.x + v.y + v.z + v.w;
  float q = v.x * v.x + v.y * v.y + v.z * v.z + v.w * v.w;
#pragma unroll
  for (int o = 1; o < 64; o <<= 1) {
    s += __shfl_xor(s, o);
    q += __shfl_xor(q, o);
  }
  __shared__ float red[8];
  int wv = tid >> 6;
  if ((tid & 63) == 0) { red[wv] = s; red[4 + wv] = q; }
  __syncthreads();
  s = red[0] + red[1] + red[2] + red[3];
  q = red[4] + red[5] + red[6] + red[7];
  float mu = s * (1.f / 1024.f);
  float var = q * (1.f / 1024.f) - mu * mu;
  float rs = rsqrtf(var + 1e-5f);
  float4 wv4 = ((const float4*)w)[tid];
  float4 bv4 = ((const float4*)b)[tid];
  ushort4 o;
  o.x = f32_bf16((v.x - mu) * rs * wv4.x + bv4.x);
  o.y = f32_bf16((v.y - mu) * rs * wv4.y + bv4.y);
  o.z = f32_bf16((v.z - mu) * rs * wv4.z + bv4.z);
  o.w = f32_bf16((v.w - mu) * rs * wv4.w + bv4.w);
  ((ushort4*)(xn + (size_t)row * D_MODEL))[tid] = o;
}

// ---------------- GEMM: C[M][N] = A[M][K] * B[N][K]^T (bf16 in) ----------------
// 2-phase pipelined: double-buffered LDS, next-tile global_load_lds issued BEFORE
// current tile's ds_read+MFMA, ONE __syncthreads per K-step after the MFMAs
// (its vmcnt(0) drain lands after the loads had the compute phase to retire).
// EPI: 0 = plain, 1 = softplus(v + bias[col])
// PARTIAL: write f32 partial tile at C + kz*M*N. OBF: write bf16.
template <int BN, int EPI, bool PARTIAL, bool OBF>
__global__ __launch_bounds__(256) void gemm_bt(const unsigned short* __restrict__ A,
                                               const unsigned short* __restrict__ B,
                                               void* __restrict__ Cout, int M, int N, int K,
                                               int klen, const float* __restrict__ extra) {
  constexpr int NN = BN / 32;       // per-wave 16-col accumulator count
  constexpr int ASZ = 128 * 32;
  constexpr int BSZ = BN * 32;
  __shared__ unsigned short As[2 * ASZ];
  __shared__ unsigned short Bs[2 * BSZ];
  const int tid = threadIdx.x;
  const int lane = tid & 63, wave = tid >> 6;
  const int wr = wave >> 1, wc = wave & 1;
  const int rl = lane & 15, kg = lane >> 4;
  // XCD-aware swizzle on flattened (bx,by); all our grids have nwg % 8 == 0
  const int gx = gridDim.x;
  const int nwg = gx * gridDim.y;
  const int bid = blockIdx.y * gx + blockIdx.x;
  const int swz = (bid & 7) * (nwg >> 3) + (bid >> 3);
  const int bx = swz % gx, by = swz / gx, kz = blockIdx.z;
  const unsigned short* Ab = A + (size_t)by * 128 * K;
  const unsigned short* Bb = B + (size_t)bx * BN * K;
  const int srow = wave * 16 + (lane >> 2);
  const int scol = (lane & 3) * 8;
  const int kbeg = kz * klen;
  const int nsteps = klen / 32;

  auto STAGE = [&](int buf, int k0) {
    unsigned short* A_ = As + buf * ASZ;
    unsigned short* B_ = Bs + buf * BSZ;
    const unsigned short* ga = Ab + (size_t)srow * K + k0 + scol;
    const unsigned short* gb = Bb + (size_t)srow * K + k0 + scol;
    stage16(ga, A_ + wave * 512);
    stage16(ga + (size_t)64 * K, A_ + 2048 + wave * 512);
    stage16(gb, B_ + wave * 512);
    if constexpr (BN == 128) stage16(gb + (size_t)64 * K, B_ + 2048 + wave * 512);
  };

  floatx4 acc[4][NN] = {};
  int cur = 0;
  STAGE(0, kbeg);
  __syncthreads();  // prologue: buf0 ready
  for (int s = 0; s < nsteps; ++s) {
    if (s + 1 < nsteps) STAGE(cur ^ 1, kbeg + (s + 1) * 32);  // prefetch next
    const unsigned short* A_ = As + cur * ASZ;
    const unsigned short* B_ = Bs + cur * BSZ;
    bf16x8 af[4], bfr[NN];
#pragma unroll
    for (int m = 0; m < 4; ++m)
      af[m] = *(const bf16x8*)&A_[(wr * 64 + m * 16 + rl) * 32 + kg * 8];
#pragma unroll
    for (int n = 0; n < NN; ++n)
      bfr[n] = *(const bf16x8*)&B_[(wc * (BN / 2) + n * 16 + rl) * 32 + kg * 8];
#pragma unroll
    for (int m = 0; m < 4; ++m)
#pragma unroll
      for (int n = 0; n < NN; ++n)
        acc[m][n] = __builtin_amdgcn_mfma_f32_16x16x32_bf16(af[m], bfr[n], acc[m][n], 0, 0, 0);
    __syncthreads();  // next buf landed (vmcnt0) + all waves done reading cur
    cur ^= 1;
  }
  float* Cf = PARTIAL ? (float*)Cout + (size_t)kz * M * N : (float*)Cout;
  unsigned short* Cb = (unsigned short*)Cout;
#pragma unroll
  for (int m = 0; m < 4; ++m) {
#pragma unroll
    for (int n = 0; n < NN; ++n) {
      int col = bx * BN + wc * (BN / 2) + n * 16 + rl;
#pragma unroll
      for (int j = 0; j < 4; ++j) {
        int rowg = by * 128 + wr * 64 + m * 16 + kg * 4 + j;
        float v = acc[m][n][j];
        if (!PARTIAL && EPI == 1) {
          v += extra[col];
          v = (v > 20.f) ? v : log1pf(__expf(v));
        }
        if (OBF)
          Cb[(size_t)rowg * N + col] = f32_bf16(v);
        else
          Cf[(size_t)rowg * N + col] = v;
      }
    }
  }
}

// ---------------- split-K combines ----------------
template <int NS, int EPI>
__global__ __launch_bounds__(256) void combine_k(const float* __restrict__ part,
                                                 float* __restrict__ out, int MN4,
                                                 const float* __restrict__ extra) {
  int i = blockIdx.x * 256 + threadIdx.x;
  if (i >= MN4) return;
  float4 s = ((const float4*)part)[i];
#pragma unroll
  for (int z = 1; z < NS; ++z) {
    float4 p = ((const float4*)(part + (size_t)z * MN4 * 4))[i];
    s.x += p.x; s.y += p.y; s.z += p.z; s.w += p.w;
  }
  if (EPI == 2) {
    float4 e = ((const float4*)extra)[i];
    s.x += e.x; s.y += e.y; s.z += e.z; s.w += e.w;
  }
  ((float4*)out)[i] = s;
}

// x-proj: proj = sum_z part[z]; also emit dtlow bf16 for cols [0,64)
__global__ __launch_bounds__(256) void combine_xp(const float* __restrict__ part,
                                                  float* __restrict__ proj,
                                                  unsigned short* __restrict__ dtlow) {
  int i = blockIdx.x * 256 + threadIdx.x;  // < 2048*128/4
  float4 s = ((const float4*)part)[i];
#pragma unroll
  for (int z = 1; z < 16; ++z) {
    float4 p = ((const float4*)(part + (size_t)z * L_SEQ * 128))[i];
    s.x += p.x; s.y += p.y; s.z += p.z; s.w += p.w;
  }
  ((float4*)proj)[i] = s;
  int c4 = i & 31;  // (col/4)
  if (c4 < 16) {
    int r = i >> 5;
    ushort4 o;
    o.x = f32_bf16(s.x); o.y = f32_bf16(s.y); o.z = f32_bf16(s.z); o.w = f32_bf16(s.w);
    ((ushort4*)dtlow)[r * 16 + c4] = o;
  }
}

// ---------------- causal depthwise conv (k=4) + SiLU (bf16 in/out) ----------------
__global__ __launch_bounds__(256) void conv_silu_kernel(const unsigned short* __restrict__ xzb,
                                                        const float* __restrict__ cw,
                                                        const float* __restrict__ cb,
                                                        unsigned short* __restrict__ xconv_bf) {
  int d = blockIdx.x * 256 + threadIdx.x;  // 0..2047
  int lb = blockIdx.y * 8;
  float w0 = cw[d * 4 + 0], w1 = cw[d * 4 + 1], w2 = cw[d * 4 + 2], w3 = cw[d * 4 + 3];
  float bias = cb[d];
  float xm3 = (lb >= 3) ? bf16_f32(xzb[(size_t)(lb - 3) * 4096 + d]) : 0.f;
  float xm2 = (lb >= 2) ? bf16_f32(xzb[(size_t)(lb - 2) * 4096 + d]) : 0.f;
  float xm1 = (lb >= 1) ? bf16_f32(xzb[(size_t)(lb - 1) * 4096 + d]) : 0.f;
#pragma unroll
  for (int j = 0; j < 8; ++j) {
    int l = lb + j;
    float cur = bf16_f32(xzb[(size_t)l * 4096 + d]);
    float s = bias + w0 * xm3 + w1 * xm2 + w2 * xm1 + w3 * cur;
    s = s / (1.f + __expf(-s));
    xconv_bf[(size_t)l * 2048 + d] = f32_bf16(s);
    xm3 = xm2; xm2 = xm1; xm1 = cur;
  }
}

// ---------------- chunked selective scan (lane owns channel d, 16 states in regs) ----------------
__global__ __launch_bounds__(256) void scan_passA(const float* __restrict__ dt,
                                                  const unsigned short* __restrict__ xc_bf,
                                                  const float* __restrict__ proj,
                                                  const float* __restrict__ A_log,
                                                  float* __restrict__ Pprod,
                                                  float* __restrict__ hend) {
  __shared__ float bc[T_CHUNK][32];
  const int tid = threadIdx.x;
  const int c = blockIdx.y;
  const int t0 = c * T_CHUNK;
  {
    int t = tid >> 3, j = (tid & 7) * 4;
    *(float4*)&bc[t][j] = *(const float4*)&proj[(size_t)(t0 + t) * 128 + 64 + j];
  }
  __syncthreads();
  const int d = blockIdx.x * 256 + tid;
  float A[16];
#pragma unroll
  for (int q = 0; q < 4; ++q) {
    float4 al = ((const float4*)(A_log + (size_t)d * 16))[q];
    A[q * 4 + 0] = -__expf(al.x);
    A[q * 4 + 1] = -__expf(al.y);
    A[q * 4 + 2] = -__expf(al.z);
    A[q * 4 + 3] = -__expf(al.w);
  }
  float h[16], P[16];
#pragma unroll
  for (int n = 0; n < 16; ++n) { h[n] = 0.f; P[n] = 1.f; }

  const int TC = 8;
  float pd[TC];
  unsigned short px[TC];
#pragma unroll
  for (int j = 0; j < TC; ++j) {
    pd[j] = dt[(size_t)(t0 + j) * 2048 + d];
    px[j] = xc_bf[(size_t)(t0 + j) * 2048 + d];
  }
  for (int tb = 0; tb < T_CHUNK; tb += TC) {
    float cd[TC], cx[TC];
#pragma unroll
    for (int j = 0; j < TC; ++j) { cd[j] = pd[j]; cx[j] = bf16_f32(px[j]); }
    if (tb + TC < T_CHUNK) {
#pragma unroll
      for (int j = 0; j < TC; ++j) {
        pd[j] = dt[(size_t)(t0 + tb + TC + j) * 2048 + d];
        px[j] = xc_bf[(size_t)(t0 + tb + TC + j) * 2048 + d];
      }
    }
#pragma unroll
    for (int j = 0; j < TC; ++j) {
      int t = tb + j;
      float dtv = cd[j];
      float dtx = dtv * cx[j];
      float4 B0 = *(const float4*)&bc[t][0];
      float4 B1 = *(const float4*)&bc[t][4];
      float4 B2 = *(const float4*)&bc[t][8];
      float4 B3 = *(const float4*)&bc[t][12];
      float Bv[16] = {B0.x, B0.y, B0.z, B0.w, B1.x, B1.y, B1.z, B1.w,
                      B2.x, B2.y, B2.z, B2.w, B3.x, B3.y, B3.z, B3.w};
#pragma unroll
      for (int n = 0; n < 16; ++n) {
        float da = __expf(dtv * A[n]);
        P[n] *= da;
        h[n] = __builtin_fmaf(da, h[n], dtx * Bv[n]);
      }
    }
  }
  size_t base = ((size_t)c * 2048 + d) * 16;
#pragma unroll
  for (int q = 0; q < 4; ++q) {
    ((float4*)(Pprod + base))[q] = make_float4(P[q * 4], P[q * 4 + 1], P[q * 4 + 2], P[q * 4 + 3]);
    ((float4*)(hend + base))[q] = make_float4(h[q * 4], h[q * 4 + 1], h[q * 4 + 2], h[q * 4 + 3]);
  }
}

__global__ __launch_bounds__(256) void scan_prefix(const float* __restrict__ Pprod,
                                                   const float* __restrict__ hend,
                                                   float* __restrict__ hinit) {
  int i = blockIdx.x * 256 + threadIdx.x;  // 0..32767 = d*16+n
  float h = 0.f;
  const int TC = 8;
  float pP[TC], pH[TC];
#pragma unroll
  for (int j = 0; j < TC; ++j) {
    pP[j] = Pprod[((size_t)j << 15) + i];
    pH[j] = hend[((size_t)j << 15) + i];
  }
  for (int cb = 0; cb < N_CHUNK; cb += TC) {
    float cP[TC], cH[TC];
#pragma unroll
    for (int j = 0; j < TC; ++j) { cP[j] = pP[j]; cH[j] = pH[j]; }
    if (cb + TC < N_CHUNK) {
#pragma unroll
      for (int j = 0; j < TC; ++j) {
        pP[j] = Pprod[((size_t)(cb + TC + j) << 15) + i];
        pH[j] = hend[((size_t)(cb + TC + j) << 15) + i];
      }
    }
#pragma unroll
    for (int j = 0; j < TC; ++j) {
      hinit[((size_t)(cb + j) << 15) + i] = h;
      h = __builtin_fmaf(cP[j], h, cH[j]);
    }
  }
}

__global__ __launch_bounds__(256) void scan_passB(const float* __restrict__ dt,
                                                  const unsigned short* __restrict__ xc_bf,
                                                  const float* __restrict__ proj,
                                                  const unsigned short* __restrict__ xzb,
                                                  const float* __restrict__ A_log,
                                                  const float* __restrict__ Dskip,
                                                  const float* __restrict__ hinit,
                                                  unsigned short* __restrict__ ybf) {
  __shared__ float bc[T_CHUNK][32];
  const int tid = threadIdx.x;
  const int c = blockIdx.y;
  const int t0 = c * T_CHUNK;
  {
    int t = tid >> 3, j = (tid & 7) * 4;
    *(float4*)&bc[t][j] = *(const float4*)&proj[(size_t)(t0 + t) * 128 + 64 + j];
  }
  __syncthreads();
  const int d = blockIdx.x * 256 + tid;
  float A[16];
#pragma unroll
  for (int q = 0; q < 4; ++q) {
    float4 al = ((const float4*)(A_log + (size_t)d * 16))[q];
    A[q * 4 + 0] = -__expf(al.x);
    A[q * 4 + 1] = -__expf(al.y);
    A[q * 4 + 2] = -__expf(al.z);
    A[q * 4 + 3] = -__expf(al.w);
  }
  const float Dv = Dskip[d];
  float h[16];
  {
    size_t base = ((size_t)c * 2048 + d) * 16;
#pragma unroll
    for (int q = 0; q < 4; ++q) {
      float4 hv = ((const float4*)(hinit + base))[q];
      h[q * 4 + 0] = hv.x; h[q * 4 + 1] = hv.y; h[q * 4 + 2] = hv.z; h[q * 4 + 3] = hv.w;
    }
  }
  const int TC = 8;
  float pd[TC];
  unsigned short px[TC], pz[TC];
#pragma unroll
  for (int j = 0; j < TC; ++j) {
    pd[j] = dt[(size_t)(t0 + j) * 2048 + d];
    px[j] = xc_bf[(size_t)(t0 + j) * 2048 + d];
    pz[j] = xzb[(size_t)(t0 + j) * 4096 + 2048 + d];
  }
  for (int tb = 0; tb < T_CHUNK; tb += TC) {
    float cd[TC], cx[TC], cz[TC];
#pragma unroll
    for (int j = 0; j < TC; ++j) {
      cd[j] = pd[j]; cx[j] = bf16_f32(px[j]); cz[j] = bf16_f32(pz[j]);
    }
    if (tb + TC < T_CHUNK) {
#pragma unroll
      for (int j = 0; j < TC; ++j) {
        pd[j] = dt[(size_t)(t0 + tb + TC + j) * 2048 + d];
        px[j] = xc_bf[(size_t)(t0 + tb + TC + j) * 2048 + d];
        pz[j] = xzb[(size_t)(t0 + tb + TC + j) * 4096 + 2048 + d];
      }
    }
#pragma unroll
    for (int j = 0; j < TC; ++j) {
      int t = tb + j;
      float dtv = cd[j];
      float xv = cx[j];
      float dtx = dtv * xv;
      float4 B0 = *(const float4*)&bc[t][0];
      float4 B1 = *(const float4*)&bc[t][4];
      float4 B2 = *(const float4*)&bc[t][8];
      float4 B3 = *(const float4*)&bc[t][12];
      float4 C0 = *(const float4*)&bc[t][16];
      float4 C1 = *(const float4*)&bc[t][20];
      float4 C2 = *(const float4*)&bc[t][24];
      float4 C3 = *(const float4*)&bc[t][28];
      float Bv[16] = {B0.x, B0.y, B0.z, B0.w, B1.x, B1.y, B1.z, B1.w,
                      B2.x, B2.y, B2.z, B2.w, B3.x, B3.y, B3.z, B3.w};
      float Cv[16] = {C0.x, C0.y, C0.z, C0.w, C1.x, C1.y, C1.z, C1.w,
                      C2.x, C2.y, C2.z, C2.w, C3.x, C3.y, C3.z, C3.w};
      float y = 0.f;
#pragma unroll
      for (int n = 0; n < 16; ++n) {
        float da = __expf(dtv * A[n]);
        h[n] = __builtin_fmaf(da, h[n], dtx * Bv[n]);
        y = __builtin_fmaf(h[n], Cv[n], y);
      }
      float zv = cz[j];
      float yv = y + xv * Dv;
      yv *= zv / (1.f + __expf(-zv));
      ybf[(size_t)(t0 + t) * 2048 + d] = f32_bf16(yv);
    }
  }
}

// ---------------- launcher ----------------
extern "C" void kernel_launch(void* const* d_in, const int* in_sizes, int n_in,
                              void* d_out, int out_size, void* d_ws, size_t ws_size,
                              hipStream_t stream) {
  const float* x      = (const float*)d_in[0];
  const float* ln_w   = (const float*)d_in[1];
  const float* ln_b   = (const float*)d_in[2];
  const float* W_in   = (const float*)d_in[3];
  const float* conv_w = (const float*)d_in[4];
  const float* conv_b = (const float*)d_in[5];
  const float* W_xproj= (const float*)d_in[6];
  const float* W_dt   = (const float*)d_in[7];
  const float* b_dt   = (const float*)d_in[8];
  const float* A_log  = (const float*)d_in[9];
  const float* Dskip  = (const float*)d_in[10];
  const float* W_out  = (const float*)d_in[11];
  float* out = (float*)d_out;

  char* ws = (char*)d_ws;
  size_t off = 0;
  auto alloc = [&](size_t bytes) {
    void* p = ws + off;
    off = (off + bytes + 255) & ~(size_t)255;
    return p;
  };
  unsigned short* xn_bf      = (unsigned short*)alloc((size_t)L_SEQ * D_MODEL * 2);
  unsigned short* W_in_bf    = (unsigned short*)alloc((size_t)2 * D_INNER * D_MODEL * 2);
  unsigned short* W_xprojp   = (unsigned short*)alloc((size_t)128 * D_INNER * 2);
  unsigned short* W_dt_bf    = (unsigned short*)alloc((size_t)D_INNER * DT_RANK * 2);
  unsigned short* W_out_bf   = (unsigned short*)alloc((size_t)D_MODEL * D_INNER * 2);
  unsigned short* xz_bf      = (unsigned short*)alloc((size_t)L_SEQ * 2 * D_INNER * 2);
  unsigned short* xconv_bf   = (unsigned short*)alloc((size_t)L_SEQ * D_INNER * 2);
  float*          proj       = (float*)alloc((size_t)L_SEQ * 128 * 4);
  unsigned short* dtlow_bf   = (unsigned short*)alloc((size_t)L_SEQ * DT_RANK * 2);
  float*          dtf        = (float*)alloc((size_t)L_SEQ * D_INNER * 4);
  unsigned short* y_bf       = (unsigned short*)alloc((size_t)L_SEQ * D_INNER * 2);
  float*          Pprod      = (float*)alloc((size_t)N_CHUNK * D_INNER * D_STATE * 4);
  float*          hend       = (float*)alloc((size_t)N_CHUNK * D_INNER * D_STATE * 4);
  float*          hinit      = (float*)alloc((size_t)N_CHUNK * D_INNER * D_STATE * 4);
  float*          part_xp    = (float*)alloc((size_t)16 * L_SEQ * 128 * 4);     // 16 MB
  float*          part_out   = (float*)alloc((size_t)2 * L_SEQ * D_MODEL * 4);  // 16 MB

  // fused weight converts
  cvt_weights<<<(NI4 + NO4 + ND4 + 255) / 256, 256, 0, stream>>>(W_in, W_out, W_dt,
                                                                 W_in_bf, W_out_bf, W_dt_bf);
  cvt_pad_xproj<<<128 * 2048 / 256, 256, 0, stream>>>(W_xproj, W_xprojp);

  // layernorm -> xn bf16
  ln_kernel<<<L_SEQ, 256, 0, stream>>>(x, ln_w, ln_b, xn_bf);

  // in_proj: xz = xn @ W_in^T  (M=2048, N=4096, K=1024) -> bf16; BN=128, 512 blocks
  gemm_bt<128, 0, false, true><<<dim3(32, 16, 1), 256, 0, stream>>>(xn_bf, W_in_bf, xz_bf, L_SEQ, 4096, 1024, 1024, nullptr);

  // depthwise conv + SiLU on xc = xz[:, :2048] (bf16 -> bf16)
  conv_silu_kernel<<<dim3(D_INNER / 256, L_SEQ / 8), 256, 0, stream>>>(xz_bf, conv_w, conv_b, xconv_bf);

  // x_proj: proj = xconv @ W_xprojp^T  (M=2048, N=128(pad), K=2048), split-K 16; 512 blocks
  gemm_bt<64, 0, true, false><<<dim3(2, 16, 16), 256, 0, stream>>>(xconv_bf, W_xprojp, part_xp, L_SEQ, 128, 2048, 128, nullptr);
  combine_xp<<<(L_SEQ * 128 / 4) / 256, 256, 0, stream>>>(part_xp, proj, dtlow_bf);

  // dt = softplus(dtlow @ W_dt^T + b_dt)  (M=2048, N=2048, K=64) -> f32; 512 blocks
  gemm_bt<64, 1, false, false><<<dim3(32, 16, 1), 256, 0, stream>>>(dtlow_bf, W_dt_bf, dtf, L_SEQ, 2048, 64, 64, b_dt);

  // chunked selective scan (transposed: lane owns a channel, 16 states in registers)
  scan_passA<<<dim3(D_INNER / 256, N_CHUNK), 256, 0, stream>>>(dtf, xconv_bf, proj, A_log, Pprod, hend);
  scan_prefix<<<128, 256, 0, stream>>>(Pprod, hend, hinit);
  scan_passB<<<dim3(D_INNER / 256, N_CHUNK), 256, 0, stream>>>(dtf, xconv_bf, proj, xz_bf, A_log, Dskip, hinit, y_bf);

  // out_proj (M=2048, N=1024, K=2048), split-K 2; 512 blocks; combine adds residual
  gemm_bt<64, 0, true, false><<<dim3(16, 16, 2), 256, 0, stream>>>(y_bf, W_out_bf, part_out, L_SEQ, 1024, 2048, 1024, nullptr);
  combine_k<2, 2><<<(L_SEQ * D_MODEL / 4) / 256, 256, 0, stream>>>(part_out, out, L_SEQ * D_MODEL / 4, x);
}